// Round 8
// baseline (367.364 us; speedup 1.0000x reference)
//
#include <hip/hip_runtime.h>
#include <hip/hip_bf16.h>
#include <math.h>

// Problem: T=1024, B=4, H=16, D=64, C=1024.
#define T_SEQ 1024
#define NB 4
#define NH 16
#define DD 64
#define CC 1024

typedef __attribute__((ext_vector_type(8))) short short8;   // 8 x bf16 (4 VGPR)
typedef __attribute__((ext_vector_type(4))) float floatx4;  // MFMA C/D
typedef __attribute__((ext_vector_type(4))) unsigned short ushort4v;

#define MFMA(a, b, c) __builtin_amdgcn_mfma_f32_16x16x32_bf16((a), (b), (c), 0, 0, 0)

__device__ inline float bf2f(unsigned short u) {
  union { unsigned int i; float f; } c; c.i = ((unsigned int)u) << 16; return c.f;
}
__device__ inline unsigned short f2bf(float x) {
  union { float f; unsigned int i; } c; c.f = x;
  unsigned int u = c.i;
  u += 0x7fff + ((u >> 16) & 1);   // RNE (inputs are finite)
  return (unsigned short)(u >> 16);
}

// async global->LDS, 16B per lane; LDS dest = wave-uniform base + lane*16
__device__ __forceinline__ void gload_lds16(const void* g, void* l) {
  __builtin_amdgcn_global_load_lds(
      (const __attribute__((address_space(1))) unsigned int*)g,
      (__attribute__((address_space(3))) unsigned int*)l, 16, 0, 0);
}

// lgkm-only barrier: waits LDS ops but NOT vmcnt, so register prefetch
// (global loads to VGPRs) stays in flight across the barrier. Safe when all
// inter-thread communication flows through LDS (true for attn_kernel: no
// global_load_lds there). __syncthreads() would emit s_waitcnt vmcnt(0)
// and drain the prefetch (m97 finding). sched_barrier(0) fences compiler
// code motion (rule #18).
__device__ __forceinline__ void bar_lgkm() {
  __builtin_amdgcn_sched_barrier(0);
  asm volatile("s_waitcnt lgkmcnt(0)" ::: "memory");
  __builtin_amdgcn_s_barrier();
  __builtin_amdgcn_sched_barrier(0);
}

// ---------------------------------------------------------------------------
// Convert pass: fp32 -> bf16 for q/k/v inputs, pos_emb (padded to 2048 rows),
// and the 5 weight matrices. One vec8 per thread.
// ---------------------------------------------------------------------------
__global__ __launch_bounds__(256) void convert_kernel(
    const float* __restrict__ q, const float* __restrict__ k,
    const float* __restrict__ v, const float* __restrict__ pe_in,
    const float* __restrict__ wq, const float* __restrict__ wk,
    const float* __restrict__ wv, const float* __restrict__ wp,
    const float* __restrict__ wo,
    unsigned short* __restrict__ qo, unsigned short* __restrict__ ko,
    unsigned short* __restrict__ vo, unsigned short* __restrict__ po,
    unsigned short* __restrict__ wqo, unsigned short* __restrict__ wko,
    unsigned short* __restrict__ wvo, unsigned short* __restrict__ wpo,
    unsigned short* __restrict__ woo)
{
  const int i = blockIdx.x * 256 + threadIdx.x;  // vec8 index
  const float* src; unsigned short* dst; int off;
  if      (i < 524288)  { src = q;     dst = qo;  off = i; }
  else if (i < 1048576) { src = k;     dst = ko;  off = i - 524288; }
  else if (i < 1572864) { src = v;     dst = vo;  off = i - 1048576; }
  else if (i < 1834880) { src = pe_in; dst = po;  off = i - 1572864; }
  else if (i < 1965952) { src = wq;    dst = wqo; off = i - 1834880; }
  else if (i < 2097024) { src = wk;    dst = wko; off = i - 1965952; }
  else if (i < 2228096) { src = wv;    dst = wvo; off = i - 2097024; }
  else if (i < 2359168) { src = wp;    dst = wpo; off = i - 2228096; }
  else if (i < 2490240) { src = wo;    dst = woo; off = i - 2359168; }
  else {  // zero-fill pos_emb pad row 2047 (128 vec8 = 1024 elems)
    const int j = i - 2490240;
    *(short8*)&po[2047 * 1024 + j * 8] = (short8){0, 0, 0, 0, 0, 0, 0, 0};
    return;
  }
  const float4 a0 = *(const float4*)(src + (size_t)off * 8);
  const float4 a1 = *(const float4*)(src + (size_t)off * 8 + 4);
  short8 val = (short8){(short)f2bf(a0.x), (short)f2bf(a0.y), (short)f2bf(a0.z), (short)f2bf(a0.w),
                        (short)f2bf(a1.x), (short)f2bf(a1.y), (short)f2bf(a1.z), (short)f2bf(a1.w)};
  *(short8*)&dst[(size_t)off * 8] = val;
}

// ---------------------------------------------------------------------------
// bf16 MFMA GEMM core, T3-minimal 2-phase: double-buffered LDS, next tile's
// global_load_lds issued BEFORE computing the current tile, ONE barrier per
// K-step. (Keeps __syncthreads: global_load_lds NEEDS the vmcnt drain for
// correctness.)  C[m,n] = sum_k A[m,k]*W[n,k] (+bias[n]).  LDS: 32 KB.
// ---------------------------------------------------------------------------
template <int OUT_BF16>
__device__ __forceinline__ void gemm_core_db(
    const unsigned short* __restrict__ A, const unsigned short* __restrict__ Wt,
    const float* __restrict__ bias, void* __restrict__ Cv,
    unsigned short* As0, unsigned short* Bs0,
    unsigned short* As1, unsigned short* Bs1,
    int N, int K, int bm, int bn)
{
  const int tid = threadIdx.x;
  const int lane = tid & 63;
  const int w = tid >> 6;
  const int l15 = lane & 15, quad = lane >> 4;
  const int rw = (w >> 1) * 64, cw = (w & 1) * 64;

  floatx4 acc[4][4];
#pragma unroll
  for (int i = 0; i < 4; ++i)
#pragma unroll
    for (int j = 0; j < 4; ++j) acc[i][j] = (floatx4){0.f, 0.f, 0.f, 0.f};

  const int lrow = lane >> 2, lcol = (lane & 3) * 8;
  const unsigned short* Ag = A + (size_t)(bm + w * 32 + lrow) * K + lcol;
  const unsigned short* Wg = Wt + (size_t)(bn + w * 32 + lrow) * K + lcol;

#define G_STAGE(AS, BS, KOFF)                                   \
  do {                                                          \
    gload_lds16(Ag + (KOFF), (AS) + w * 1024);                  \
    gload_lds16(Ag + 16 * K + (KOFF), (AS) + w * 1024 + 512);   \
    gload_lds16(Wg + (KOFF), (BS) + w * 1024);                  \
    gload_lds16(Wg + 16 * K + (KOFF), (BS) + w * 1024 + 512);   \
  } while (0)

#define G_COMPUTE(AS, BS)                                               \
  do {                                                                  \
    short8 af[4], bfr[4];                                               \
    _Pragma("unroll")                                                   \
    for (int i = 0; i < 4; ++i)                                         \
      af[i] = *(short8*)&(AS)[(rw + i * 16 + l15) * 32 + quad * 8];     \
    _Pragma("unroll")                                                   \
    for (int j = 0; j < 4; ++j)                                         \
      bfr[j] = *(short8*)&(BS)[(cw + j * 16 + l15) * 32 + quad * 8];    \
    _Pragma("unroll")                                                   \
    for (int i = 0; i < 4; ++i)                                         \
      _Pragma("unroll")                                                 \
      for (int j = 0; j < 4; ++j)                                       \
        acc[i][j] = MFMA(af[i], bfr[j], acc[i][j]);                     \
  } while (0)

  // prologue: stage k=0 into buf0
  G_STAGE(As0, Bs0, 0);
  __syncthreads();

  for (int k0 = 0; k0 < K; k0 += 64) {
    if (k0 + 32 < K) G_STAGE(As1, Bs1, k0 + 32);   // issue next (async)
    G_COMPUTE(As0, Bs0);                           // compute current
    __syncthreads();                               // drains vmcnt -> buf1 ready
    if (k0 + 64 < K) G_STAGE(As0, Bs0, k0 + 64);
    G_COMPUTE(As1, Bs1);
    __syncthreads();
  }
#undef G_STAGE
#undef G_COMPUTE

#pragma unroll
  for (int j = 0; j < 4; ++j) {
    const int col = bn + cw + j * 16 + l15;
    const float bj = bias ? bias[col] : 0.f;
#pragma unroll
    for (int i = 0; i < 4; ++i) {
      const int row0 = bm + rw + i * 16 + quad * 4;
#pragma unroll
      for (int reg = 0; reg < 4; ++reg) {
        const float v = acc[i][j][reg] + bj;
        if (OUT_BF16)
          ((unsigned short*)Cv)[(size_t)(row0 + reg) * N + col] = f2bf(v);
        else
          ((float*)Cv)[(size_t)(row0 + reg) * N + col] = v;
      }
    }
  }
}

struct GemmJob { const unsigned short* A; const unsigned short* Wt;
                 const float* bias; unsigned short* C; int mtiles; };
struct GemmJobs { GemmJob j[4]; };

// Fused Q,K,V,P projection GEMMs (z picks job; P has 16 m-tiles).
__global__ __launch_bounds__(256) void gemm_qkvp(GemmJobs jobs) {
  __shared__ __align__(16) unsigned short As0[128 * 32];
  __shared__ __align__(16) unsigned short Bs0[128 * 32];
  __shared__ __align__(16) unsigned short As1[128 * 32];
  __shared__ __align__(16) unsigned short Bs1[128 * 32];
  GemmJob jb = jobs.j[blockIdx.z];
  if ((int)blockIdx.y >= jb.mtiles) return;
  gemm_core_db<1>(jb.A, jb.Wt, jb.bias, jb.C, As0, Bs0, As1, Bs1,
                  1024, 1024, blockIdx.y * 128, blockIdx.x * 128);
}

template <int OUT_BF16>
__global__ __launch_bounds__(256) void gemm_one(
    const unsigned short* __restrict__ A, const unsigned short* __restrict__ Wt,
    const float* __restrict__ bias, void* __restrict__ Cv) {
  __shared__ __align__(16) unsigned short As0[128 * 32];
  __shared__ __align__(16) unsigned short Bs0[128 * 32];
  __shared__ __align__(16) unsigned short As1[128 * 32];
  __shared__ __align__(16) unsigned short Bs1[128 * 32];
  gemm_core_db<OUT_BF16>(A, Wt, bias, Cv, As0, Bs0, As1, Bs1,
                         1024, 1024, blockIdx.y * 128, blockIdx.x * 128);
}

// ---------------------------------------------------------------------------
// Fused: transpose V (blocks 0..511) + rank-1 bias dots (blocks 512..895).
// ---------------------------------------------------------------------------
__global__ __launch_bounds__(256) void transpose_precompute(
    const unsigned short* __restrict__ vb, unsigned short* __restrict__ vT,
    const unsigned short* __restrict__ kb, const unsigned short* __restrict__ pb,
    const float* __restrict__ pbu, const float* __restrict__ pbv,
    float* __restrict__ uk, float* __restrict__ vp)
{
  __shared__ __align__(16) unsigned short Lt[64 * 136];
  const int bid = blockIdx.x;
  const int tid = threadIdx.x;
  if (bid < 512) {
    const int t0 = (bid & 7) * 128;
    const int h = (bid >> 3) & 15, b = bid >> 7;
#pragma unroll
    for (int cc = 0; cc < 4; ++cc) {
      const int idx = tid + cc * 256;
      const int r = idx >> 3, pc = idx & 7;
      short8 val = *(const short8*)(vb + ((size_t)((t0 + r) * 4 + b)) * 1024 + h * 64 + pc * 8);
#pragma unroll
      for (int e = 0; e < 8; ++e)
        Lt[(pc * 8 + e) * 136 + r] = (unsigned short)val[e];
    }
    __syncthreads();
#pragma unroll
    for (int cc = 0; cc < 4; ++cc) {
      const int idx = tid + cc * 256;
      const int d = idx >> 4, tc = idx & 15;
      short8 v2 = *(short8*)&Lt[d * 136 + tc * 8];
      *(short8*)(vT + ((size_t)((b * 16 + h) * 64 + d)) * 1024 + t0 + tc * 8) = v2;
    }
  } else {
    const int i = (bid - 512) * 256 + tid;
    if (i < 65536) {
      const int b = i >> 14, h = (i >> 10) & 15, s = i & 1023;
      const unsigned short* kr = kb + ((size_t)(s * 4 + b)) * 1024 + h * 64;
      const float* ur = pbu + h * 64;
      float sum = 0.f;
#pragma unroll
      for (int c = 0; c < 8; ++c) {
        short8 kv = *(const short8*)(kr + c * 8);
#pragma unroll
        for (int e = 0; e < 8; ++e) sum += bf2f((unsigned short)kv[e]) * ur[c * 8 + e];
      }
      uk[i] = sum;
    } else if (i < 98304) {
      const int j = i - 65536;
      const int idx = j >> 4, h = j & 15;
      const unsigned short* pr = pb + (size_t)idx * 1024 + h * 64;
      const float* vr = pbv + h * 64;
      float sum = 0.f;
#pragma unroll
      for (int c = 0; c < 8; ++c) {
        short8 pv = *(const short8*)(pr + c * 8);
#pragma unroll
        for (int e = 0; e < 8; ++e) sum += bf2f((unsigned short)pv[e]) * vr[c * 8 + e];
      }
      vp[(idx << 4) + h] = sum;
    }
  }
}

// ---------------------------------------------------------------------------
// Fused rel-pos MFMA attention v12 = r7 attn (BDW 148, 40960 B LDS, merged
// Phase-3, s-step 128) with ONE change: __syncthreads -> bar_lgkm.
// __syncthreads drains vmcnt(0), killing the cross-iteration K/P register
// prefetch (its whole purpose). All inter-thread data in this kernel flows
// through LDS, so waiting lgkmcnt only is sufficient; the ~20 prefetch
// loads stay in flight across B_a..B_e and their L2/HBM latency hides
// behind Phases 2-5. Single-variable A/B vs r7 (r6 confounded this with
// an s-step change).
// ---------------------------------------------------------------------------
#define BDW 148  // BDs row stride in floats

__global__ __launch_bounds__(256) void attn_kernel(
    const unsigned short* __restrict__ qb, const unsigned short* __restrict__ kb,
    const unsigned short* __restrict__ pb, const unsigned short* __restrict__ vT,
    const float* __restrict__ uk, const float* __restrict__ vp,
    unsigned short* __restrict__ xb)
{
  // 10240 floats = 40960 B exactly (4 blocks/CU).
  __shared__ __align__(16) float SMEM_ALL[10240];
  float* BDf  = SMEM_ALL;                 // [64][BDW] fp32 (Phases 1-2)
  unsigned short* Pb = (unsigned short*)SMEM_ALL;  // [64][136] bf16 (Phases 4-5)
  float* uk_s  = SMEM_ALL + 9472;         // 128
  float* vp_w  = SMEM_ALL + 9600;         // 192
  float* pmax0 = SMEM_ALL + 9792;         // 64
  float* pmax1 = SMEM_ALL + 9856;         // 64
  float* psum0 = SMEM_ALL + 9920;         // 64
  float* psum1 = SMEM_ALL + 9984;         // 64
  float* m_rowA = SMEM_ALL + 10048;       // 64 (ping)
  float* m_rowB = SMEM_ALL + 10112;       // 64 (pong)
  float* l_row  = SMEM_ALL + 10176;       // 64

  const int tid = threadIdx.x;
  const int lane = tid & 63;
  const int w = tid >> 6;
  const int l15 = lane & 15, quad = lane >> 4;
  const int th = w & 1, sh = w >> 1;

  // XCD swizzle: cluster the 16 q-tiles of one (b,h) on one XCD.
  const int flat = blockIdx.x + (blockIdx.y << 4) + (blockIdx.z << 8);
  const int x8 = flat & 7, s8 = flat >> 3;
  const int hb = x8 * 8 + (s8 >> 4);
  const int t0 = (s8 & 15) * 64;
  const int b = hb >> 4, h = hb & 15;

  // Q as MFMA B-operand: B[k=d][n=t], lane n=l15, k=quad*8+j. qf[ttile][kstep]
  short8 qf[2][2];
#pragma unroll
  for (int tt = 0; tt < 2; ++tt)
#pragma unroll
    for (int kk = 0; kk < 2; ++kk) {
      const int t = t0 + th * 32 + tt * 16 + l15;
      qf[tt][kk] = *(const short8*)(qb + ((size_t)(t * 4 + b)) * 1024 + h * 64 + kk * 32 + quad * 8);
    }

  floatx4 of[2][2];  // O[t-tile][d-tile], rows t=quad*4+reg, cols d=l15
#pragma unroll
  for (int i = 0; i < 2; ++i)
#pragma unroll
    for (int j = 0; j < 2; ++j) of[i][j] = (floatx4){0.f, 0.f, 0.f, 0.f};

  if (tid < 64) { m_rowA[tid] = -3.0e38f; l_row[tid] = 0.f; }
  bar_lgkm();

  // per-wave fragment pointers (depend only on s0; same lane pattern each iter)
  const unsigned short* kbase = kb + ((size_t)((sh * 64 + l15) * 4 + b)) * 1024 + h * 64;
  const unsigned short* pbase0 = pb + ((size_t)(sh * 96 + l15)) * 1024 + h * 64;

  // prefetched fragments for the CURRENT iteration
  short8 kf[4][2], pf[6][2];
  {
    const int w0 = 0 - t0 + 960;
#pragma unroll
    for (int st4 = 0; st4 < 4; ++st4) {
      const unsigned short* kr = kbase + (size_t)(st4 * 16) * 4096;
      kf[st4][0] = *(const short8*)(kr + quad * 8);
      kf[st4][1] = *(const short8*)(kr + 32 + quad * 8);
    }
#pragma unroll
    for (int jt = 0; jt < 6; ++jt) {
      const int sA = sh * 96 + jt * 16 + th * 32;  // ssum at tt=0 (s0-independent)
      if (sA <= 16 || sA > 190) continue;          // pf[jt] never consumed
      const unsigned short* pr = pbase0 + (size_t)(w0 + jt * 16) * 1024;
      pf[jt][0] = *(const short8*)(pr + quad * 8);
      pf[jt][1] = *(const short8*)(pr + 32 + quad * 8);
    }
  }

  for (int s0 = 0; s0 < 1024; s0 += 128) {
    const int w0 = s0 - t0 + 960;
    const int par = (s0 >> 7) & 1;
    float* m_prev = par ? m_rowB : m_rowA;
    float* m_next = par ? m_rowA : m_rowB;

    if (tid < 128) uk_s[tid] = uk[((b * 16 + h) << 10) + s0 + tid];
    if (tid < 192) vp_w[tid] = vp[(((size_t)(w0 + tid)) << 4) + h];

    // ---- Phase 1: BD MFMA (prefetched pf) -> one float4/tile + AC MFMA ----
#pragma unroll
    for (int jt = 0; jt < 6; ++jt) {
      const int jjbase = sh * 96 + jt * 16;
#pragma unroll
      for (int tt = 0; tt < 2; ++tt) {
        const int tbase = th * 32 + tt * 16;
        const int ssum = jjbase + tbase;
        // tile's s-range = [ssum-63, ssum-33]; skip if fully outside [0,128)
        if (ssum <= 32 || ssum > 190) continue;   // wave-uniform scalar branch
        floatx4 z = (floatx4){0.f, 0.f, 0.f, 0.f};
        z = MFMA(pf[jt][0], qf[tt][0], z);
        z = MFMA(pf[jt][1], qf[tt][1], z);
        const int tloc = tbase + l15;
        *(float4*)&BDf[tloc * BDW + (ssum - 48) + quad * 4] =
            make_float4(z[0], z[1], z[2], z[3]);
      }
    }

    floatx4 st[4][2];
#pragma unroll
    for (int stile = 0; stile < 4; ++stile) {
#pragma unroll
      for (int tt = 0; tt < 2; ++tt) {
        floatx4 z = (floatx4){0.f, 0.f, 0.f, 0.f};
        z = MFMA(kf[stile][0], qf[tt][0], z);
        z = MFMA(kf[stile][1], qf[tt][1], z);
        st[stile][tt] = z;
      }
    }

    // ---- issue next-iteration K/P fragment loads (in flight across barriers) ----
    {
      const int s0n = (s0 + 128 < 1024) ? (s0 + 128) : 0;  // last iter: dummy reload
      const int w0n = s0n - t0 + 960;
#pragma unroll
      for (int st4 = 0; st4 < 4; ++st4) {
        const unsigned short* kr = kbase + (size_t)(s0n + st4 * 16) * 4096;
        kf[st4][0] = *(const short8*)(kr + quad * 8);
        kf[st4][1] = *(const short8*)(kr + 32 + quad * 8);
      }
#pragma unroll
      for (int jt = 0; jt < 6; ++jt) {
        const int sA = sh * 96 + jt * 16 + th * 32;
        if (sA <= 16 || sA > 190) continue;      // pf[jt] never consumed
        const unsigned short* pr = pbase0 + (size_t)(w0n + jt * 16) * 1024;
        pf[jt][0] = *(const short8*)(pr + quad * 8);
        pf[jt][1] = *(const short8*)(pr + 32 + quad * 8);
      }
    }
    bar_lgkm();  // B_a: BDs visible (prefetch stays in flight)

    // ---- Phase 2: assemble scores + per-t local max ----
    float lmax[2] = {-3.0e38f, -3.0e38f};
#pragma unroll
    for (int stile = 0; stile < 4; ++stile)
#pragma unroll
      for (int tt = 0; tt < 2; ++tt) {
        const int tloc = th * 32 + tt * 16 + l15;
#pragma unroll
        for (int reg = 0; reg < 4; ++reg) {
          const int sloc = sh * 64 + stile * 16 + quad * 4 + reg;
          const int jj = sloc - tloc + 63;
          float v = 0.125f * (st[stile][tt][reg] + BDf[tloc * BDW + sloc - l15 + 15] +
                              uk_s[sloc] + vp_w[jj]);
          st[stile][tt][reg] = v;
          lmax[tt] = fmaxf(lmax[tt], v);
        }
      }
#pragma unroll
    for (int tt = 0; tt < 2; ++tt) {
      lmax[tt] = fmaxf(lmax[tt], __shfl_xor(lmax[tt], 16));
      lmax[tt] = fmaxf(lmax[tt], __shfl_xor(lmax[tt], 32));
    }
    if (quad == 0) {
      float* pm = sh ? pmax1 : pmax0;
      pm[th * 32 + l15] = lmax[0];
      pm[th * 32 + 16 + l15] = lmax[1];
    }
    bar_lgkm();  // B_b: BDs reads done; pmax visible

    // ---- Phase 3 (merged): per-thread redundant m/alpha from pmax+m_prev ----
    float mn_keep = 0.f;
    if (tid < 64) {
      const float mo = m_prev[tid];
      mn_keep = fmaxf(mo, fmaxf(pmax0[tid], pmax1[tid]));
      m_next[tid] = mn_keep;    // read only next iteration (after its B_b)
    }
    float mt[2];
#pragma unroll
    for (int tt = 0; tt < 2; ++tt) {
      const int r = th * 32 + tt * 16 + l15;
      mt[tt] = fmaxf(m_prev[r], fmaxf(pmax0[r], pmax1[r]));
    }

    // ---- Phase 4: P=exp, Pb write (unions over dead BDs), psum, O rescale ----
    float lsum[2] = {0.f, 0.f};
#pragma unroll
    for (int stile = 0; stile < 4; ++stile)
#pragma unroll
      for (int tt = 0; tt < 2; ++tt) {
        float p0 = __expf(st[stile][tt][0] - mt[tt]);
        float p1 = __expf(st[stile][tt][1] - mt[tt]);
        float p2 = __expf(st[stile][tt][2] - mt[tt]);
        float p3 = __expf(st[stile][tt][3] - mt[tt]);
        lsum[tt] += p0 + p1 + p2 + p3;
        const int tloc = th * 32 + tt * 16 + l15;
        const int sb = sh * 64 + stile * 16 + quad * 4;
        ushort4v pk = (ushort4v){f2bf(p0), f2bf(p1), f2bf(p2), f2bf(p3)};
        *(ushort4v*)&Pb[tloc * 136 + sb] = pk;
      }
#pragma unroll
    for (int tt = 0; tt < 2; ++tt) {
      lsum[tt] += __shfl_xor(lsum[tt], 16);
      lsum[tt] += __shfl_xor(lsum[tt], 32);
    }
    if (quad == 0) {
      float* ps = sh ? psum1 : psum0;
      ps[th * 32 + l15] = lsum[0];
      ps[th * 32 + 16 + l15] = lsum[1];
    }
    // O rescale: alpha recomputed per-thread (float4 reads, 8 expf)
#pragma unroll
    for (int tt = 0; tt < 2; ++tt) {
      const int base = th * 32 + tt * 16 + quad * 4;
      const float4 mo4 = *(const float4*)&m_prev[base];
      const float4 p04 = *(const float4*)&pmax0[base];
      const float4 p14 = *(const float4*)&pmax1[base];
#pragma unroll
      for (int reg = 0; reg < 4; ++reg) {
        const float mo = ((const float*)&mo4)[reg];
        const float mn = fmaxf(mo, fmaxf(((const float*)&p04)[reg],
                                         ((const float*)&p14)[reg]));
        const float ar = __expf(mo - mn);
        of[tt][0][reg] *= ar;
        of[tt][1][reg] *= ar;
      }
    }
    bar_lgkm();  // B_d: Pb + psum visible

    // ---- Phase 5: l update + PV MFMA (V loads here) ----
    if (tid < 64) {
      const float alpha = __expf(m_prev[tid] - mn_keep);
      l_row[tid] = l_row[tid] * alpha + psum0[tid] + psum1[tid];
    }
#pragma unroll
    for (int kk2 = 0; kk2 < 4; ++kk2) {
      short8 pa[2], vf[2];
#pragma unroll
      for (int tt = 0; tt < 2; ++tt)
        pa[tt] = *(short8*)&Pb[(th * 32 + tt * 16 + l15) * 136 + kk2 * 32 + quad * 8];
#pragma unroll
      for (int dt = 0; dt < 2; ++dt)
        vf[dt] = *(const short8*)(vT + ((size_t)((b * 16 + h) * 64 + sh * 32 + dt * 16 + l15)) * 1024 +
                                  s0 + kk2 * 32 + quad * 8);
#pragma unroll
      for (int tt = 0; tt < 2; ++tt)
#pragma unroll
        for (int dt = 0; dt < 2; ++dt)
          of[tt][dt] = MFMA(pa[tt], vf[dt], of[tt][dt]);
    }
    bar_lgkm();  // B_e: Pb reads done before next-iter BDs writes
  }

#pragma unroll
  for (int tt = 0; tt < 2; ++tt)
#pragma unroll
    for (int reg = 0; reg < 4; ++reg) {
      const int t = th * 32 + tt * 16 + quad * 4 + reg;
      const float il = 1.f / l_row[t];
#pragma unroll
      for (int dt = 0; dt < 2; ++dt) {
        const int d = sh * 32 + dt * 16 + l15;
        xb[((size_t)((t0 + t) * 4 + b)) * 1024 + h * 64 + d] = f2bf(of[tt][dt][reg] * il);
      }
    }
}

// ---------------------------------------------------------------------------
extern "C" void kernel_launch(void* const* d_in, const int* in_sizes, int n_in,
                              void* d_out, int out_size, void* d_ws, size_t ws_size,
                              hipStream_t stream) {
  const float* query   = (const float*)d_in[0];
  const float* key_    = (const float*)d_in[1];
  const float* value   = (const float*)d_in[2];
  const float* pos_emb = (const float*)d_in[3];
  const float* Wq  = (const float*)d_in[4];
  const float* bq  = (const float*)d_in[5];
  const float* Wk  = (const float*)d_in[6];
  const float* bk  = (const float*)d_in[7];
  const float* Wv  = (const float*)d_in[8];
  const float* bv  = (const float*)d_in[9];
  const float* Wp  = (const float*)d_in[10];
  const float* Wo  = (const float*)d_in[11];
  const float* bo  = (const float*)d_in[12];
  const float* pbu = (const float*)d_in[13];
  const float* pbv = (const float*)d_in[14];
  float* out = (float*)d_out;

  // workspace (ushort elements), ~69.6 MB total
  unsigned short* U = (unsigned short*)d_ws;
  unsigned short* qin = U;                   // bf16 query   (later: attn out xb)
  unsigned short* kin = U + 4194304;         // bf16 key
  unsigned short* vin = U + 8388608;         // bf16 value
  unsigned short* pe  = U + 12582912;        // bf16 pos_emb 2048 rows (later: vTb)
  unsigned short* wq  = U + 14680064;
  unsigned short* wk  = U + 15728640;
  unsigned short* wv  = U + 16777216;
  unsigned short* wp  = U + 17825792;
  unsigned short* wo  = U + 18874368;
  unsigned short* qb  = U + 19922944;        // Q proj
  unsigned short* kb  = U + 24117248;        // K proj
  unsigned short* pb  = U + 28311552;        // P proj
  unsigned short* vpo = U + 30408704;        // V proj
  unsigned short* vTb = pe;                  // aliases pe+wq+wk (dead after projections)
  unsigned short* xb  = qin;                 // attn out (qin dead after projections)
  float* fbase = (float*)(U + 34603008);
  float* uk = fbase;                         // 65536 floats
  float* vp = fbase + 65536;                 // 32768 floats

  const dim3 blk(256);

  // 1. convert everything to bf16 (one HBM-bound pass)
  convert_kernel<<<dim3(9728), blk, 0, stream>>>(
      query, key_, value, pos_emb, Wq, Wk, Wv, Wp, Wo,
      qin, kin, vin, pe, wq, wk, wv, wp, wo);

  // 2. fused Q,K,V,P projections (896 active blocks), 2-phase pipelined
  GemmJobs jobs;
  jobs.j[0] = GemmJob{qin, wq, bq, qb, 32};
  jobs.j[1] = GemmJob{kin, wk, bk, kb, 32};
  jobs.j[2] = GemmJob{vin, wv, bv, vpo, 32};
  jobs.j[3] = GemmJob{pe,  wp, nullptr, pb, 16};
  gemm_qkvp<<<dim3(8, 32, 4), blk, 0, stream>>>(jobs);

  // 3. fused transpose V + rank-1 bias dots (one launch)
  transpose_precompute<<<dim3(896), blk, 0, stream>>>(
      vpo, vTb, kb, pb, pbu, pbv, uk, vp);

  // 4. fused attention (writes into dead qin buffer)
  attn_kernel<<<dim3(16, 16, 4), blk, 0, stream>>>(qb, kb, pb, vTb, uk, vp, xb);

  // 5. output projection -> fp32 d_out, 2-phase pipelined
  gemm_one<0><<<dim3(8, 32), blk, 0, stream>>>(xb, wo, bo, out);
}

// Round 9
// 317.921 us; speedup vs baseline: 1.1555x; 1.1555x over previous
//
#include <hip/hip_runtime.h>
#include <hip/hip_bf16.h>
#include <math.h>

// Problem: T=1024, B=4, H=16, D=64, C=1024.
#define T_SEQ 1024
#define NB 4
#define NH 16
#define DD 64
#define CC 1024

typedef __attribute__((ext_vector_type(8))) short short8;   // 8 x bf16 (4 VGPR)
typedef __attribute__((ext_vector_type(4))) float floatx4;  // MFMA C/D
typedef __attribute__((ext_vector_type(4))) unsigned short ushort4v;

#define MFMA(a, b, c) __builtin_amdgcn_mfma_f32_16x16x32_bf16((a), (b), (c), 0, 0, 0)

__device__ inline float bf2f(unsigned short u) {
  union { unsigned int i; float f; } c; c.i = ((unsigned int)u) << 16; return c.f;
}
__device__ inline unsigned short f2bf(float x) {
  union { float f; unsigned int i; } c; c.f = x;
  unsigned int u = c.i;
  u += 0x7fff + ((u >> 16) & 1);   // RNE (inputs are finite)
  return (unsigned short)(u >> 16);
}

// async global->LDS, 16B per lane; LDS dest = wave-uniform base + lane*16
__device__ __forceinline__ void gload_lds16(const void* g, void* l) {
  __builtin_amdgcn_global_load_lds(
      (const __attribute__((address_space(1))) unsigned int*)g,
      (__attribute__((address_space(3))) unsigned int*)l, 16, 0, 0);
}

// ---------------------------------------------------------------------------
// Convert pass: fp32 -> bf16 for q/k/v inputs, pos_emb (padded to 2048 rows),
// and the 5 weight matrices. One vec8 per thread.
// ---------------------------------------------------------------------------
__global__ __launch_bounds__(256) void convert_kernel(
    const float* __restrict__ q, const float* __restrict__ k,
    const float* __restrict__ v, const float* __restrict__ pe_in,
    const float* __restrict__ wq, const float* __restrict__ wk,
    const float* __restrict__ wv, const float* __restrict__ wp,
    const float* __restrict__ wo,
    unsigned short* __restrict__ qo, unsigned short* __restrict__ ko,
    unsigned short* __restrict__ vo, unsigned short* __restrict__ po,
    unsigned short* __restrict__ wqo, unsigned short* __restrict__ wko,
    unsigned short* __restrict__ wvo, unsigned short* __restrict__ wpo,
    unsigned short* __restrict__ woo)
{
  const int i = blockIdx.x * 256 + threadIdx.x;  // vec8 index
  const float* src; unsigned short* dst; int off;
  if      (i < 524288)  { src = q;     dst = qo;  off = i; }
  else if (i < 1048576) { src = k;     dst = ko;  off = i - 524288; }
  else if (i < 1572864) { src = v;     dst = vo;  off = i - 1048576; }
  else if (i < 1834880) { src = pe_in; dst = po;  off = i - 1572864; }
  else if (i < 1965952) { src = wq;    dst = wqo; off = i - 1834880; }
  else if (i < 2097024) { src = wk;    dst = wko; off = i - 1965952; }
  else if (i < 2228096) { src = wv;    dst = wvo; off = i - 2097024; }
  else if (i < 2359168) { src = wp;    dst = wpo; off = i - 2228096; }
  else if (i < 2490240) { src = wo;    dst = woo; off = i - 2359168; }
  else {  // zero-fill pos_emb pad row 2047 (128 vec8 = 1024 elems)
    const int j = i - 2490240;
    *(short8*)&po[2047 * 1024 + j * 8] = (short8){0, 0, 0, 0, 0, 0, 0, 0};
    return;
  }
  const float4 a0 = *(const float4*)(src + (size_t)off * 8);
  const float4 a1 = *(const float4*)(src + (size_t)off * 8 + 4);
  short8 val = (short8){(short)f2bf(a0.x), (short)f2bf(a0.y), (short)f2bf(a0.z), (short)f2bf(a0.w),
                        (short)f2bf(a1.x), (short)f2bf(a1.y), (short)f2bf(a1.z), (short)f2bf(a1.w)};
  *(short8*)&dst[(size_t)off * 8] = val;
}

// ---------------------------------------------------------------------------
// bf16 MFMA GEMM core, depth-2 pipelined (T4): 4 LDS buffers, stage t+2
// issued while computing stage t, counted s_waitcnt vmcnt(8) (drains only the
// oldest stage) + raw s_barrier -> ONE barrier per K-step and every load gets
// ~2 compute-phases of slack (vs depth-1's ~1 phase < L2 latency).
// Race-freedom: stage t+2 overwrites the buffer of stage t-2, whose compute
// finished before barrier t-1 in all waves' program order.
// sched_barrier(0) after s_barrier pins ds_reads (they read other waves'
// staged rows; per-wave vmcnt only covers own loads).
// C[m,n] = sum_k A[m,k]*W[n,k] (+bias[n]).  LDS: 8 x 8 KB = 64 KB.
// Requires K % 128 == 0 and K >= 192 (here K = 1024).
// ---------------------------------------------------------------------------
template <int OUT_BF16>
__device__ __forceinline__ void gemm_core_p4(
    const unsigned short* __restrict__ A, const unsigned short* __restrict__ Wt,
    const float* __restrict__ bias, void* __restrict__ Cv,
    unsigned short* SM, int N, int K, int bm, int bn)
{
  const int tid = threadIdx.x;
  const int lane = tid & 63;
  const int w = tid >> 6;
  const int l15 = lane & 15, quad = lane >> 4;
  const int rw = (w >> 1) * 64, cw = (w & 1) * 64;

  floatx4 acc[4][4];
#pragma unroll
  for (int i = 0; i < 4; ++i)
#pragma unroll
    for (int j = 0; j < 4; ++j) acc[i][j] = (floatx4){0.f, 0.f, 0.f, 0.f};

  const int lrow = lane >> 2, lcol = (lane & 3) * 8;
  const unsigned short* Ag = A + (size_t)(bm + w * 32 + lrow) * K + lcol;
  const unsigned short* Wg = Wt + (size_t)(bn + w * 32 + lrow) * K + lcol;

#define ASX(i) (SM + (i) * 4096)
#define BSX(i) (SM + 16384 + (i) * 4096)

#define G_STAGE(i, KOFF)                                            \
  do {                                                              \
    gload_lds16(Ag + (KOFF), ASX(i) + w * 1024);                    \
    gload_lds16(Ag + 16 * K + (KOFF), ASX(i) + w * 1024 + 512);     \
    gload_lds16(Wg + (KOFF), BSX(i) + w * 1024);                    \
    gload_lds16(Wg + 16 * K + (KOFF), BSX(i) + w * 1024 + 512);     \
  } while (0)

#define G_WAITBAR(NN)                                               \
  do {                                                              \
    asm volatile("s_waitcnt vmcnt(" #NN ")" ::: "memory");          \
    __builtin_amdgcn_s_barrier();                                   \
    __builtin_amdgcn_sched_barrier(0);                              \
  } while (0)

#define G_COMPUTE(bi)                                                   \
  do {                                                                  \
    short8 af[4], bfr[4];                                               \
    _Pragma("unroll")                                                   \
    for (int i = 0; i < 4; ++i)                                         \
      af[i] = *(short8*)&(ASX(bi))[(rw + i * 16 + l15) * 32 + quad * 8];\
    _Pragma("unroll")                                                   \
    for (int j = 0; j < 4; ++j)                                         \
      bfr[j] = *(short8*)&(BSX(bi))[(cw + j * 16 + l15) * 32 + quad * 8];\
    _Pragma("unroll")                                                   \
    for (int i = 0; i < 4; ++i)                                         \
      _Pragma("unroll")                                                 \
      for (int j = 0; j < 4; ++j)                                       \
        acc[i][j] = MFMA(af[i], bfr[j], acc[i][j]);                     \
  } while (0)

  // prologue: stages 0 and 1 in flight
  G_STAGE(0, 0);
  G_STAGE(1, 32);

  // main: 4 K-steps per body; compute stage t, issue stage t+2
  for (int k0 = 0; k0 < K - 128; k0 += 128) {
    G_STAGE(2, k0 + 64);  G_WAITBAR(8); G_COMPUTE(0);
    G_STAGE(3, k0 + 96);  G_WAITBAR(8); G_COMPUTE(1);
    G_STAGE(0, k0 + 128); G_WAITBAR(8); G_COMPUTE(2);
    G_STAGE(1, k0 + 160); G_WAITBAR(8); G_COMPUTE(3);
  }
  // epilogue: stages K/32-4 .. K/32-1
  G_STAGE(2, K - 64);  G_WAITBAR(8); G_COMPUTE(0);
  G_STAGE(3, K - 32);  G_WAITBAR(8); G_COMPUTE(1);
  G_WAITBAR(4); G_COMPUTE(2);
  G_WAITBAR(0); G_COMPUTE(3);

#undef G_STAGE
#undef G_WAITBAR
#undef G_COMPUTE
#undef ASX
#undef BSX

#pragma unroll
  for (int j = 0; j < 4; ++j) {
    const int col = bn + cw + j * 16 + l15;
    const float bj = bias ? bias[col] : 0.f;
#pragma unroll
    for (int i = 0; i < 4; ++i) {
      const int row0 = bm + rw + i * 16 + quad * 4;
#pragma unroll
      for (int reg = 0; reg < 4; ++reg) {
        const float v = acc[i][j][reg] + bj;
        if (OUT_BF16)
          ((unsigned short*)Cv)[(size_t)(row0 + reg) * N + col] = f2bf(v);
        else
          ((float*)Cv)[(size_t)(row0 + reg) * N + col] = v;
      }
    }
  }
}

struct GemmJob { const unsigned short* A; const unsigned short* Wt;
                 const float* bias; unsigned short* C; int mtiles; };
struct GemmJobs { GemmJob j[4]; };

// Fused Q,K,V,P projection GEMMs (z picks job; P has 16 m-tiles).
__global__ __launch_bounds__(256) void gemm_qkvp(GemmJobs jobs) {
  __shared__ __align__(16) unsigned short SM[8 * 4096];  // 64 KB
  GemmJob jb = jobs.j[blockIdx.z];
  if ((int)blockIdx.y >= jb.mtiles) return;
  gemm_core_p4<1>(jb.A, jb.Wt, jb.bias, jb.C, SM, 1024, 1024,
                  blockIdx.y * 128, blockIdx.x * 128);
}

template <int OUT_BF16>
__global__ __launch_bounds__(256) void gemm_one(
    const unsigned short* __restrict__ A, const unsigned short* __restrict__ Wt,
    const float* __restrict__ bias, void* __restrict__ Cv) {
  __shared__ __align__(16) unsigned short SM[8 * 4096];  // 64 KB
  gemm_core_p4<OUT_BF16>(A, Wt, bias, Cv, SM, 1024, 1024,
                         blockIdx.y * 128, blockIdx.x * 128);
}

// ---------------------------------------------------------------------------
// Fused: transpose V (blocks 0..511) + rank-1 bias dots (blocks 512..895).
// ---------------------------------------------------------------------------
__global__ __launch_bounds__(256) void transpose_precompute(
    const unsigned short* __restrict__ vb, unsigned short* __restrict__ vT,
    const unsigned short* __restrict__ kb, const unsigned short* __restrict__ pb,
    const float* __restrict__ pbu, const float* __restrict__ pbv,
    float* __restrict__ uk, float* __restrict__ vp)
{
  __shared__ __align__(16) unsigned short Lt[64 * 136];
  const int bid = blockIdx.x;
  const int tid = threadIdx.x;
  if (bid < 512) {
    const int t0 = (bid & 7) * 128;
    const int h = (bid >> 3) & 15, b = bid >> 7;
#pragma unroll
    for (int cc = 0; cc < 4; ++cc) {
      const int idx = tid + cc * 256;
      const int r = idx >> 3, pc = idx & 7;
      short8 val = *(const short8*)(vb + ((size_t)((t0 + r) * 4 + b)) * 1024 + h * 64 + pc * 8);
#pragma unroll
      for (int e = 0; e < 8; ++e)
        Lt[(pc * 8 + e) * 136 + r] = (unsigned short)val[e];
    }
    __syncthreads();
#pragma unroll
    for (int cc = 0; cc < 4; ++cc) {
      const int idx = tid + cc * 256;
      const int d = idx >> 4, tc = idx & 15;
      short8 v2 = *(short8*)&Lt[d * 136 + tc * 8];
      *(short8*)(vT + ((size_t)((b * 16 + h) * 64 + d)) * 1024 + t0 + tc * 8) = v2;
    }
  } else {
    const int i = (bid - 512) * 256 + tid;
    if (i < 65536) {
      const int b = i >> 14, h = (i >> 10) & 15, s = i & 1023;
      const unsigned short* kr = kb + ((size_t)(s * 4 + b)) * 1024 + h * 64;
      const float* ur = pbu + h * 64;
      float sum = 0.f;
#pragma unroll
      for (int c = 0; c < 8; ++c) {
        short8 kv = *(const short8*)(kr + c * 8);
#pragma unroll
        for (int e = 0; e < 8; ++e) sum += bf2f((unsigned short)kv[e]) * ur[c * 8 + e];
      }
      uk[i] = sum;
    } else if (i < 98304) {
      const int j = i - 65536;
      const int idx = j >> 4, h = j & 15;
      const unsigned short* pr = pb + (size_t)idx * 1024 + h * 64;
      const float* vr = pbv + h * 64;
      float sum = 0.f;
#pragma unroll
      for (int c = 0; c < 8; ++c) {
        short8 pv = *(const short8*)(pr + c * 8);
#pragma unroll
        for (int e = 0; e < 8; ++e) sum += bf2f((unsigned short)pv[e]) * vr[c * 8 + e];
      }
      vp[(idx << 4) + h] = sum;
    }
  }
}

// ---------------------------------------------------------------------------
// Fused rel-pos MFMA attention (r7 best, ~130 µs): BDW 148 conflict-free BD
// writes; exact-fit 40960 B LDS; merged Phase-3 (m_row ping-pong, redundant
// per-thread m/alpha); 4 __syncthreads/iter, s-step 128.
// r8's lgkm-only barrier A/B REGRESSED (VGPR 128->136, occ 21->11%) -> the
// vmcnt-drain theory is falsified; this structure is the attn local optimum.
// ---------------------------------------------------------------------------
#define BDW 148  // BDs row stride in floats

__global__ __launch_bounds__(256) void attn_kernel(
    const unsigned short* __restrict__ qb, const unsigned short* __restrict__ kb,
    const unsigned short* __restrict__ pb, const unsigned short* __restrict__ vT,
    const float* __restrict__ uk, const float* __restrict__ vp,
    unsigned short* __restrict__ xb)
{
  // 10240 floats = 40960 B exactly (4 blocks/CU).
  __shared__ __align__(16) float SMEM_ALL[10240];
  float* BDf  = SMEM_ALL;                 // [64][BDW] fp32 (Phases 1-2)
  unsigned short* Pb = (unsigned short*)SMEM_ALL;  // [64][136] bf16 (Phases 4-5)
  float* uk_s  = SMEM_ALL + 9472;         // 128
  float* vp_w  = SMEM_ALL + 9600;         // 192
  float* pmax0 = SMEM_ALL + 9792;         // 64
  float* pmax1 = SMEM_ALL + 9856;         // 64
  float* psum0 = SMEM_ALL + 9920;         // 64
  float* psum1 = SMEM_ALL + 9984;         // 64
  float* m_rowA = SMEM_ALL + 10048;       // 64 (ping)
  float* m_rowB = SMEM_ALL + 10112;       // 64 (pong)
  float* l_row  = SMEM_ALL + 10176;       // 64

  const int tid = threadIdx.x;
  const int lane = tid & 63;
  const int w = tid >> 6;
  const int l15 = lane & 15, quad = lane >> 4;
  const int th = w & 1, sh = w >> 1;

  // XCD swizzle: cluster the 16 q-tiles of one (b,h) on one XCD.
  const int flat = blockIdx.x + (blockIdx.y << 4) + (blockIdx.z << 8);
  const int x8 = flat & 7, s8 = flat >> 3;
  const int hb = x8 * 8 + (s8 >> 4);
  const int t0 = (s8 & 15) * 64;
  const int b = hb >> 4, h = hb & 15;

  // Q as MFMA B-operand: B[k=d][n=t], lane n=l15, k=quad*8+j. qf[ttile][kstep]
  short8 qf[2][2];
#pragma unroll
  for (int tt = 0; tt < 2; ++tt)
#pragma unroll
    for (int kk = 0; kk < 2; ++kk) {
      const int t = t0 + th * 32 + tt * 16 + l15;
      qf[tt][kk] = *(const short8*)(qb + ((size_t)(t * 4 + b)) * 1024 + h * 64 + kk * 32 + quad * 8);
    }

  floatx4 of[2][2];  // O[t-tile][d-tile], rows t=quad*4+reg, cols d=l15
#pragma unroll
  for (int i = 0; i < 2; ++i)
#pragma unroll
    for (int j = 0; j < 2; ++j) of[i][j] = (floatx4){0.f, 0.f, 0.f, 0.f};

  if (tid < 64) { m_rowA[tid] = -3.0e38f; l_row[tid] = 0.f; }
  __syncthreads();

  // per-wave fragment pointers (depend only on s0; same lane pattern each iter)
  const unsigned short* kbase = kb + ((size_t)((sh * 64 + l15) * 4 + b)) * 1024 + h * 64;
  const unsigned short* pbase0 = pb + ((size_t)(sh * 96 + l15)) * 1024 + h * 64;

  // prefetched fragments for the CURRENT iteration
  short8 kf[4][2], pf[6][2];
  {
    const int w0 = 0 - t0 + 960;
#pragma unroll
    for (int st4 = 0; st4 < 4; ++st4) {
      const unsigned short* kr = kbase + (size_t)(st4 * 16) * 4096;
      kf[st4][0] = *(const short8*)(kr + quad * 8);
      kf[st4][1] = *(const short8*)(kr + 32 + quad * 8);
    }
#pragma unroll
    for (int jt = 0; jt < 6; ++jt) {
      const int sA = sh * 96 + jt * 16 + th * 32;  // ssum at tt=0 (s0-independent)
      if (sA <= 16 || sA > 190) continue;          // pf[jt] never consumed
      const unsigned short* pr = pbase0 + (size_t)(w0 + jt * 16) * 1024;
      pf[jt][0] = *(const short8*)(pr + quad * 8);
      pf[jt][1] = *(const short8*)(pr + 32 + quad * 8);
    }
  }

  for (int s0 = 0; s0 < 1024; s0 += 128) {
    const int w0 = s0 - t0 + 960;
    const int par = (s0 >> 7) & 1;
    float* m_prev = par ? m_rowB : m_rowA;
    float* m_next = par ? m_rowA : m_rowB;

    if (tid < 128) uk_s[tid] = uk[((b * 16 + h) << 10) + s0 + tid];
    if (tid < 192) vp_w[tid] = vp[(((size_t)(w0 + tid)) << 4) + h];

    // ---- Phase 1: BD MFMA (prefetched pf) -> one float4/tile + AC MFMA ----
#pragma unroll
    for (int jt = 0; jt < 6; ++jt) {
      const int jjbase = sh * 96 + jt * 16;
#pragma unroll
      for (int tt = 0; tt < 2; ++tt) {
        const int tbase = th * 32 + tt * 16;
        const int ssum = jjbase + tbase;
        // tile's s-range = [ssum-63, ssum-33]; skip if fully outside [0,128)
        if (ssum <= 32 || ssum > 190) continue;   // wave-uniform scalar branch
        floatx4 z = (floatx4){0.f, 0.f, 0.f, 0.f};
        z = MFMA(pf[jt][0], qf[tt][0], z);
        z = MFMA(pf[jt][1], qf[tt][1], z);
        const int tloc = tbase + l15;
        *(float4*)&BDf[tloc * BDW + (ssum - 48) + quad * 4] =
            make_float4(z[0], z[1], z[2], z[3]);
      }
    }

    floatx4 st[4][2];
#pragma unroll
    for (int stile = 0; stile < 4; ++stile) {
#pragma unroll
      for (int tt = 0; tt < 2; ++tt) {
        floatx4 z = (floatx4){0.f, 0.f, 0.f, 0.f};
        z = MFMA(kf[stile][0], qf[tt][0], z);
        z = MFMA(kf[stile][1], qf[tt][1], z);
        st[stile][tt] = z;
      }
    }

    // ---- issue next-iteration K/P fragment loads (in flight across barriers) ----
    {
      const int s0n = (s0 + 128 < 1024) ? (s0 + 128) : 0;  // last iter: dummy reload
      const int w0n = s0n - t0 + 960;
#pragma unroll
      for (int st4 = 0; st4 < 4; ++st4) {
        const unsigned short* kr = kbase + (size_t)(s0n + st4 * 16) * 4096;
        kf[st4][0] = *(const short8*)(kr + quad * 8);
        kf[st4][1] = *(const short8*)(kr + 32 + quad * 8);
      }
#pragma unroll
      for (int jt = 0; jt < 6; ++jt) {
        const int sA = sh * 96 + jt * 16 + th * 32;
        if (sA <= 16 || sA > 190) continue;      // pf[jt] never consumed
        const unsigned short* pr = pbase0 + (size_t)(w0n + jt * 16) * 1024;
        pf[jt][0] = *(const short8*)(pr + quad * 8);
        pf[jt][1] = *(const short8*)(pr + 32 + quad * 8);
      }
    }
    __syncthreads();  // B_a: BDs visible

    // ---- Phase 2: assemble scores + per-t local max ----
    float lmax[2] = {-3.0e38f, -3.0e38f};
#pragma unroll
    for (int stile = 0; stile < 4; ++stile)
#pragma unroll
      for (int tt = 0; tt < 2; ++tt) {
        const int tloc = th * 32 + tt * 16 + l15;
#pragma unroll
        for (int reg = 0; reg < 4; ++reg) {
          const int sloc = sh * 64 + stile * 16 + quad * 4 + reg;
          const int jj = sloc - tloc + 63;
          float v = 0.125f * (st[stile][tt][reg] + BDf[tloc * BDW + sloc - l15 + 15] +
                              uk_s[sloc] + vp_w[jj]);
          st[stile][tt][reg] = v;
          lmax[tt] = fmaxf(lmax[tt], v);
        }
      }
#pragma unroll
    for (int tt = 0; tt < 2; ++tt) {
      lmax[tt] = fmaxf(lmax[tt], __shfl_xor(lmax[tt], 16));
      lmax[tt] = fmaxf(lmax[tt], __shfl_xor(lmax[tt], 32));
    }
    if (quad == 0) {
      float* pm = sh ? pmax1 : pmax0;
      pm[th * 32 + l15] = lmax[0];
      pm[th * 32 + 16 + l15] = lmax[1];
    }
    __syncthreads();  // B_b: BDs reads done; pmax visible

    // ---- Phase 3 (merged): per-thread redundant m/alpha from pmax+m_prev ----
    float mn_keep = 0.f;
    if (tid < 64) {
      const float mo = m_prev[tid];
      mn_keep = fmaxf(mo, fmaxf(pmax0[tid], pmax1[tid]));
      m_next[tid] = mn_keep;    // read only next iteration (after its B_b)
    }
    float mt[2];
#pragma unroll
    for (int tt = 0; tt < 2; ++tt) {
      const int r = th * 32 + tt * 16 + l15;
      mt[tt] = fmaxf(m_prev[r], fmaxf(pmax0[r], pmax1[r]));
    }

    // ---- Phase 4: P=exp, Pb write (unions over dead BDs), psum, O rescale ----
    float lsum[2] = {0.f, 0.f};
#pragma unroll
    for (int stile = 0; stile < 4; ++stile)
#pragma unroll
      for (int tt = 0; tt < 2; ++tt) {
        float p0 = __expf(st[stile][tt][0] - mt[tt]);
        float p1 = __expf(st[stile][tt][1] - mt[tt]);
        float p2 = __expf(st[stile][tt][2] - mt[tt]);
        float p3 = __expf(st[stile][tt][3] - mt[tt]);
        lsum[tt] += p0 + p1 + p2 + p3;
        const int tloc = th * 32 + tt * 16 + l15;
        const int sb = sh * 64 + stile * 16 + quad * 4;
        ushort4v pk = (ushort4v){f2bf(p0), f2bf(p1), f2bf(p2), f2bf(p3)};
        *(ushort4v*)&Pb[tloc * 136 + sb] = pk;
      }
#pragma unroll
    for (int tt = 0; tt < 2; ++tt) {
      lsum[tt] += __shfl_xor(lsum[tt], 16);
      lsum[tt] += __shfl_xor(lsum[tt], 32);
    }
    if (quad == 0) {
      float* ps = sh ? psum1 : psum0;
      ps[th * 32 + l15] = lsum[0];
      ps[th * 32 + 16 + l15] = lsum[1];
    }
    // O rescale: alpha recomputed per-thread (float4 reads, 8 expf)
#pragma unroll
    for (int tt = 0; tt < 2; ++tt) {
      const int base = th * 32 + tt * 16 + quad * 4;
      const float4 mo4 = *(const float4*)&m_prev[base];
      const float4 p04 = *(const float4*)&pmax0[base];
      const float4 p14 = *(const float4*)&pmax1[base];
#pragma unroll
      for (int reg = 0; reg < 4; ++reg) {
        const float mo = ((const float*)&mo4)[reg];
        const float mn = fmaxf(mo, fmaxf(((const float*)&p04)[reg],
                                         ((const float*)&p14)[reg]));
        const float ar = __expf(mo - mn);
        of[tt][0][reg] *= ar;
        of[tt][1][reg] *= ar;
      }
    }
    __syncthreads();  // B_d: Pb + psum visible

    // ---- Phase 5: l update + PV MFMA (V loads here) ----
    if (tid < 64) {
      const float alpha = __expf(m_prev[tid] - mn_keep);
      l_row[tid] = l_row[tid] * alpha + psum0[tid] + psum1[tid];
    }
#pragma unroll
    for (int kk2 = 0; kk2 < 4; ++kk2) {
      short8 pa[2], vf[2];
#pragma unroll
      for (int tt = 0; tt < 2; ++tt)
        pa[tt] = *(short8*)&Pb[(th * 32 + tt * 16 + l15) * 136 + kk2 * 32 + quad * 8];
#pragma unroll
      for (int dt = 0; dt < 2; ++dt)
        vf[dt] = *(const short8*)(vT + ((size_t)((b * 16 + h) * 64 + sh * 32 + dt * 16 + l15)) * 1024 +
                                  s0 + kk2 * 32 + quad * 8);
#pragma unroll
      for (int tt = 0; tt < 2; ++tt)
#pragma unroll
        for (int dt = 0; dt < 2; ++dt)
          of[tt][dt] = MFMA(pa[tt], vf[dt], of[tt][dt]);
    }
    __syncthreads();  // B_e: Pb reads done before next-iter BDs writes
  }

#pragma unroll
  for (int tt = 0; tt < 2; ++tt)
#pragma unroll
    for (int reg = 0; reg < 4; ++reg) {
      const int t = th * 32 + tt * 16 + quad * 4 + reg;
      const float il = 1.f / l_row[t];
#pragma unroll
      for (int dt = 0; dt < 2; ++dt) {
        const int d = sh * 32 + dt * 16 + l15;
        xb[((size_t)((t0 + t) * 4 + b)) * 1024 + h * 64 + d] = f2bf(of[tt][dt][reg] * il);
      }
    }
}

// ---------------------------------------------------------------------------
extern "C" void kernel_launch(void* const* d_in, const int* in_sizes, int n_in,
                              void* d_out, int out_size, void* d_ws, size_t ws_size,
                              hipStream_t stream) {
  const float* query   = (const float*)d_in[0];
  const float* key_    = (const float*)d_in[1];
  const float* value   = (const float*)d_in[2];
  const float* pos_emb = (const float*)d_in[3];
  const float* Wq  = (const float*)d_in[4];
  const float* bq  = (const float*)d_in[5];
  const float* Wk  = (const float*)d_in[6];
  const float* bk  = (const float*)d_in[7];
  const float* Wv  = (const float*)d_in[8];
  const float* bv  = (const float*)d_in[9];
  const float* Wp  = (const float*)d_in[10];
  const float* Wo  = (const float*)d_in[11];
  const float* bo  = (const float*)d_in[12];
  const float* pbu = (const float*)d_in[13];
  const float* pbv = (const float*)d_in[14];
  float* out = (float*)d_out;

  // workspace (ushort elements), ~69.6 MB total
  unsigned short* U = (unsigned short*)d_ws;
  unsigned short* qin = U;                   // bf16 query   (later: attn out xb)
  unsigned short* kin = U + 4194304;         // bf16 key
  unsigned short* vin = U + 8388608;         // bf16 value
  unsigned short* pe  = U + 12582912;        // bf16 pos_emb 2048 rows (later: vTb)
  unsigned short* wq  = U + 14680064;
  unsigned short* wk  = U + 15728640;
  unsigned short* wv  = U + 16777216;
  unsigned short* wp  = U + 17825792;
  unsigned short* wo  = U + 18874368;
  unsigned short* qb  = U + 19922944;        // Q proj
  unsigned short* kb  = U + 24117248;        // K proj
  unsigned short* pb  = U + 28311552;        // P proj
  unsigned short* vpo = U + 30408704;        // V proj
  unsigned short* vTb = pe;                  // aliases pe+wq+wk (dead after projections)
  unsigned short* xb  = qin;                 // attn out (qin dead after projections)
  float* fbase = (float*)(U + 34603008);
  float* uk = fbase;                         // 65536 floats
  float* vp = fbase + 65536;                 // 32768 floats

  const dim3 blk(256);

  // 1. convert everything to bf16 (one HBM-bound pass)
  convert_kernel<<<dim3(9728), blk, 0, stream>>>(
      query, key_, value, pos_emb, Wq, Wk, Wv, Wp, Wo,
      qin, kin, vin, pe, wq, wk, wv, wp, wo);

  // 2. fused Q,K,V,P projections (896 active blocks), depth-2 pipelined
  GemmJobs jobs;
  jobs.j[0] = GemmJob{qin, wq, bq, qb, 32};
  jobs.j[1] = GemmJob{kin, wk, bk, kb, 32};
  jobs.j[2] = GemmJob{vin, wv, bv, vpo, 32};
  jobs.j[3] = GemmJob{pe,  wp, nullptr, pb, 16};
  gemm_qkvp<<<dim3(8, 32, 4), blk, 0, stream>>>(jobs);

  // 3. fused transpose V + rank-1 bias dots (one launch)
  transpose_precompute<<<dim3(896), blk, 0, stream>>>(
      vpo, vTb, kb, pb, pbu, pbv, uk, vp);

  // 4. fused attention (writes into dead qin buffer)
  attn_kernel<<<dim3(16, 16, 4), blk, 0, stream>>>(qb, kb, pb, vTb, uk, vp, xb);

  // 5. output projection -> fp32 d_out, depth-2 pipelined
  gemm_one<0><<<dim3(8, 32), blk, 0, stream>>>(xb, wo, bo, out);
}

// Round 10
// 317.356 us; speedup vs baseline: 1.1576x; 1.0018x over previous
//
#include <hip/hip_runtime.h>
#include <hip/hip_bf16.h>
#include <math.h>

// Problem: T=1024, B=4, H=16, D=64, C=1024.
#define T_SEQ 1024
#define NB 4
#define NH 16
#define DD 64
#define CC 1024

typedef __attribute__((ext_vector_type(8))) short short8;   // 8 x bf16 (4 VGPR)
typedef __attribute__((ext_vector_type(4))) float floatx4;  // MFMA C/D
typedef __attribute__((ext_vector_type(4))) unsigned short ushort4v;

#define MFMA(a, b, c) __builtin_amdgcn_mfma_f32_16x16x32_bf16((a), (b), (c), 0, 0, 0)

__device__ inline float bf2f(unsigned short u) {
  union { unsigned int i; float f; } c; c.i = ((unsigned int)u) << 16; return c.f;
}
__device__ inline unsigned short f2bf(float x) {
  union { float f; unsigned int i; } c; c.f = x;
  unsigned int u = c.i;
  u += 0x7fff + ((u >> 16) & 1);   // RNE (inputs are finite)
  return (unsigned short)(u >> 16);
}

// async global->LDS, 16B per lane; LDS dest = wave-uniform base + lane*16
__device__ __forceinline__ void gload_lds16(const void* g, void* l) {
  __builtin_amdgcn_global_load_lds(
      (const __attribute__((address_space(1))) unsigned int*)g,
      (__attribute__((address_space(3))) unsigned int*)l, 16, 0, 0);
}

// ---------------------------------------------------------------------------
// Convert pass: fp32 -> bf16 for q/k/v inputs, pos_emb (padded to 2048 rows),
// and the 5 weight matrices. One vec8 per thread.
// ---------------------------------------------------------------------------
__global__ __launch_bounds__(256) void convert_kernel(
    const float* __restrict__ q, const float* __restrict__ k,
    const float* __restrict__ v, const float* __restrict__ pe_in,
    const float* __restrict__ wq, const float* __restrict__ wk,
    const float* __restrict__ wv, const float* __restrict__ wp,
    const float* __restrict__ wo,
    unsigned short* __restrict__ qo, unsigned short* __restrict__ ko,
    unsigned short* __restrict__ vo, unsigned short* __restrict__ po,
    unsigned short* __restrict__ wqo, unsigned short* __restrict__ wko,
    unsigned short* __restrict__ wvo, unsigned short* __restrict__ wpo,
    unsigned short* __restrict__ woo)
{
  const int i = blockIdx.x * 256 + threadIdx.x;  // vec8 index
  const float* src; unsigned short* dst; int off;
  if      (i < 524288)  { src = q;     dst = qo;  off = i; }
  else if (i < 1048576) { src = k;     dst = ko;  off = i - 524288; }
  else if (i < 1572864) { src = v;     dst = vo;  off = i - 1048576; }
  else if (i < 1834880) { src = pe_in; dst = po;  off = i - 1572864; }
  else if (i < 1965952) { src = wq;    dst = wqo; off = i - 1834880; }
  else if (i < 2097024) { src = wk;    dst = wko; off = i - 1965952; }
  else if (i < 2228096) { src = wv;    dst = wvo; off = i - 2097024; }
  else if (i < 2359168) { src = wp;    dst = wpo; off = i - 2228096; }
  else if (i < 2490240) { src = wo;    dst = woo; off = i - 2359168; }
  else {  // zero-fill pos_emb pad row 2047 (128 vec8 = 1024 elems)
    const int j = i - 2490240;
    *(short8*)&po[2047 * 1024 + j * 8] = (short8){0, 0, 0, 0, 0, 0, 0, 0};
    return;
  }
  const float4 a0 = *(const float4*)(src + (size_t)off * 8);
  const float4 a1 = *(const float4*)(src + (size_t)off * 8 + 4);
  short8 val = (short8){(short)f2bf(a0.x), (short)f2bf(a0.y), (short)f2bf(a0.z), (short)f2bf(a0.w),
                        (short)f2bf(a1.x), (short)f2bf(a1.y), (short)f2bf(a1.z), (short)f2bf(a1.w)};
  *(short8*)&dst[(size_t)off * 8] = val;
}

// ---------------------------------------------------------------------------
// Depth-2 pipelined GEMM core, 8-wave (512-thread) variant: same 128x128
// tile, same 4-buffer rotation and counted-vmcnt discipline as the proven
// 256-thread core, but repartitioned so (a) per-lane staging halves
// (2 gload_lds/stage -> waits vmcnt(4/2/0)), (b) per-wave regs drop
// (acc 32, frags 24), (c) residency = 2 blocks x 8 waves = 16 waves/CU
// (2x the TLP of the 4-wave core at identical LDS).
// Each wave computes a 64x32 output sub-tile: rw=(w>>2)*64, cw=(w&3)*32.
// ---------------------------------------------------------------------------
template <int OUT_BF16>
__device__ __forceinline__ void gemm_core_p8(
    const unsigned short* __restrict__ A, const unsigned short* __restrict__ Wt,
    const float* __restrict__ bias, void* __restrict__ Cv,
    unsigned short* SM, int N, int K, int bm, int bn)
{
  const int tid = threadIdx.x;
  const int lane = tid & 63;
  const int w = tid >> 6;                 // 0..7
  const int l15 = lane & 15, quad = lane >> 4;
  const int rw = (w >> 2) * 64, cw = (w & 3) * 32;

  floatx4 acc[4][2];
#pragma unroll
  for (int i = 0; i < 4; ++i)
#pragma unroll
    for (int j = 0; j < 2; ++j) acc[i][j] = (floatx4){0.f, 0.f, 0.f, 0.f};

  const int lrow = lane >> 2, lcol = (lane & 3) * 8;  // 4 lanes per row
  const unsigned short* Ag = A + (size_t)(bm + w * 16 + lrow) * K + lcol;
  const unsigned short* Wg = Wt + (size_t)(bn + w * 16 + lrow) * K + lcol;

#define ASX(i) (SM + (i) * 4096)
#define BSX(i) (SM + 16384 + (i) * 4096)

#define G_STAGE(i, KOFF)                                \
  do {                                                  \
    gload_lds16(Ag + (KOFF), ASX(i) + w * 512);         \
    gload_lds16(Wg + (KOFF), BSX(i) + w * 512);         \
  } while (0)

#define G_WAITBAR(NN)                                   \
  do {                                                  \
    asm volatile("s_waitcnt vmcnt(" #NN ")" ::: "memory"); \
    __builtin_amdgcn_s_barrier();                       \
    __builtin_amdgcn_sched_barrier(0);                  \
  } while (0)

#define G_COMPUTE(bi)                                                    \
  do {                                                                   \
    short8 af[4], bfr[2];                                                \
    _Pragma("unroll")                                                    \
    for (int i = 0; i < 4; ++i)                                          \
      af[i] = *(short8*)&(ASX(bi))[(rw + i * 16 + l15) * 32 + quad * 8]; \
    _Pragma("unroll")                                                    \
    for (int j = 0; j < 2; ++j)                                          \
      bfr[j] = *(short8*)&(BSX(bi))[(cw + j * 16 + l15) * 32 + quad * 8];\
    _Pragma("unroll")                                                    \
    for (int i = 0; i < 4; ++i)                                          \
      _Pragma("unroll")                                                  \
      for (int j = 0; j < 2; ++j)                                        \
        acc[i][j] = MFMA(af[i], bfr[j], acc[i][j]);                      \
  } while (0)

  // prologue: stages 0 and 1 in flight (2 loads each)
  G_STAGE(0, 0);
  G_STAGE(1, 32);

  for (int k0 = 0; k0 < K - 128; k0 += 128) {
    G_STAGE(2, k0 + 64);  G_WAITBAR(4); G_COMPUTE(0);
    G_STAGE(3, k0 + 96);  G_WAITBAR(4); G_COMPUTE(1);
    G_STAGE(0, k0 + 128); G_WAITBAR(4); G_COMPUTE(2);
    G_STAGE(1, k0 + 160); G_WAITBAR(4); G_COMPUTE(3);
  }
  G_STAGE(2, K - 64);  G_WAITBAR(4); G_COMPUTE(0);
  G_STAGE(3, K - 32);  G_WAITBAR(4); G_COMPUTE(1);
  G_WAITBAR(2); G_COMPUTE(2);
  G_WAITBAR(0); G_COMPUTE(3);

#undef G_STAGE
#undef G_WAITBAR
#undef G_COMPUTE
#undef ASX
#undef BSX

#pragma unroll
  for (int j = 0; j < 2; ++j) {
    const int col = bn + cw + j * 16 + l15;
    const float bj = bias ? bias[col] : 0.f;
#pragma unroll
    for (int i = 0; i < 4; ++i) {
      const int row0 = bm + rw + i * 16 + quad * 4;
#pragma unroll
      for (int reg = 0; reg < 4; ++reg) {
        const float v = acc[i][j][reg] + bj;
        if (OUT_BF16)
          ((unsigned short*)Cv)[(size_t)(row0 + reg) * N + col] = f2bf(v);
        else
          ((float*)Cv)[(size_t)(row0 + reg) * N + col] = v;
      }
    }
  }
}

// ---------------------------------------------------------------------------
// Depth-2 pipelined GEMM core, 4-wave (256-thread) variant — r9 proven.
// Used for gemm_one (grid = 1 block/CU either way).
// ---------------------------------------------------------------------------
template <int OUT_BF16>
__device__ __forceinline__ void gemm_core_p4(
    const unsigned short* __restrict__ A, const unsigned short* __restrict__ Wt,
    const float* __restrict__ bias, void* __restrict__ Cv,
    unsigned short* SM, int N, int K, int bm, int bn)
{
  const int tid = threadIdx.x;
  const int lane = tid & 63;
  const int w = tid >> 6;
  const int l15 = lane & 15, quad = lane >> 4;
  const int rw = (w >> 1) * 64, cw = (w & 1) * 64;

  floatx4 acc[4][4];
#pragma unroll
  for (int i = 0; i < 4; ++i)
#pragma unroll
    for (int j = 0; j < 4; ++j) acc[i][j] = (floatx4){0.f, 0.f, 0.f, 0.f};

  const int lrow = lane >> 2, lcol = (lane & 3) * 8;
  const unsigned short* Ag = A + (size_t)(bm + w * 32 + lrow) * K + lcol;
  const unsigned short* Wg = Wt + (size_t)(bn + w * 32 + lrow) * K + lcol;

#define ASX(i) (SM + (i) * 4096)
#define BSX(i) (SM + 16384 + (i) * 4096)

#define G_STAGE(i, KOFF)                                            \
  do {                                                              \
    gload_lds16(Ag + (KOFF), ASX(i) + w * 1024);                    \
    gload_lds16(Ag + 16 * K + (KOFF), ASX(i) + w * 1024 + 512);     \
    gload_lds16(Wg + (KOFF), BSX(i) + w * 1024);                    \
    gload_lds16(Wg + 16 * K + (KOFF), BSX(i) + w * 1024 + 512);     \
  } while (0)

#define G_WAITBAR(NN)                                               \
  do {                                                              \
    asm volatile("s_waitcnt vmcnt(" #NN ")" ::: "memory");          \
    __builtin_amdgcn_s_barrier();                                   \
    __builtin_amdgcn_sched_barrier(0);                              \
  } while (0)

#define G_COMPUTE(bi)                                                   \
  do {                                                                  \
    short8 af[4], bfr[4];                                               \
    _Pragma("unroll")                                                   \
    for (int i = 0; i < 4; ++i)                                         \
      af[i] = *(short8*)&(ASX(bi))[(rw + i * 16 + l15) * 32 + quad * 8];\
    _Pragma("unroll")                                                   \
    for (int j = 0; j < 4; ++j)                                         \
      bfr[j] = *(short8*)&(BSX(bi))[(cw + j * 16 + l15) * 32 + quad * 8];\
    _Pragma("unroll")                                                   \
    for (int i = 0; i < 4; ++i)                                         \
      _Pragma("unroll")                                                 \
      for (int j = 0; j < 4; ++j)                                       \
        acc[i][j] = MFMA(af[i], bfr[j], acc[i][j]);                     \
  } while (0)

  G_STAGE(0, 0);
  G_STAGE(1, 32);

  for (int k0 = 0; k0 < K - 128; k0 += 128) {
    G_STAGE(2, k0 + 64);  G_WAITBAR(8); G_COMPUTE(0);
    G_STAGE(3, k0 + 96);  G_WAITBAR(8); G_COMPUTE(1);
    G_STAGE(0, k0 + 128); G_WAITBAR(8); G_COMPUTE(2);
    G_STAGE(1, k0 + 160); G_WAITBAR(8); G_COMPUTE(3);
  }
  G_STAGE(2, K - 64);  G_WAITBAR(8); G_COMPUTE(0);
  G_STAGE(3, K - 32);  G_WAITBAR(8); G_COMPUTE(1);
  G_WAITBAR(4); G_COMPUTE(2);
  G_WAITBAR(0); G_COMPUTE(3);

#undef G_STAGE
#undef G_WAITBAR
#undef G_COMPUTE
#undef ASX
#undef BSX

#pragma unroll
  for (int j = 0; j < 4; ++j) {
    const int col = bn + cw + j * 16 + l15;
    const float bj = bias ? bias[col] : 0.f;
#pragma unroll
    for (int i = 0; i < 4; ++i) {
      const int row0 = bm + rw + i * 16 + quad * 4;
#pragma unroll
      for (int reg = 0; reg < 4; ++reg) {
        const float v = acc[i][j][reg] + bj;
        if (OUT_BF16)
          ((unsigned short*)Cv)[(size_t)(row0 + reg) * N + col] = f2bf(v);
        else
          ((float*)Cv)[(size_t)(row0 + reg) * N + col] = v;
      }
    }
  }
}

struct GemmJob { const unsigned short* A; const unsigned short* Wt;
                 const float* bias; unsigned short* C; int mtiles; };
struct GemmJobs { GemmJob j[4]; };

// Fused Q,K,V,P projection GEMMs (z picks job; P has 16 m-tiles). 512 thr.
__global__ __launch_bounds__(512) void gemm_qkvp(GemmJobs jobs) {
  __shared__ __align__(16) unsigned short SM[8 * 4096];  // 64 KB
  GemmJob jb = jobs.j[blockIdx.z];
  if ((int)blockIdx.y >= jb.mtiles) return;
  gemm_core_p8<1>(jb.A, jb.Wt, jb.bias, jb.C, SM, 1024, 1024,
                  blockIdx.y * 128, blockIdx.x * 128);
}

template <int OUT_BF16>
__global__ __launch_bounds__(256) void gemm_one(
    const unsigned short* __restrict__ A, const unsigned short* __restrict__ Wt,
    const float* __restrict__ bias, void* __restrict__ Cv) {
  __shared__ __align__(16) unsigned short SM[8 * 4096];  // 64 KB
  gemm_core_p4<OUT_BF16>(A, Wt, bias, Cv, SM, 1024, 1024,
                         blockIdx.y * 128, blockIdx.x * 128);
}

// ---------------------------------------------------------------------------
// Fused: transpose V (blocks 0..511) + rank-1 bias dots (blocks 512..895).
// ---------------------------------------------------------------------------
__global__ __launch_bounds__(256) void transpose_precompute(
    const unsigned short* __restrict__ vb, unsigned short* __restrict__ vT,
    const unsigned short* __restrict__ kb, const unsigned short* __restrict__ pb,
    const float* __restrict__ pbu, const float* __restrict__ pbv,
    float* __restrict__ uk, float* __restrict__ vp)
{
  __shared__ __align__(16) unsigned short Lt[64 * 136];
  const int bid = blockIdx.x;
  const int tid = threadIdx.x;
  if (bid < 512) {
    const int t0 = (bid & 7) * 128;
    const int h = (bid >> 3) & 15, b = bid >> 7;
#pragma unroll
    for (int cc = 0; cc < 4; ++cc) {
      const int idx = tid + cc * 256;
      const int r = idx >> 3, pc = idx & 7;
      short8 val = *(const short8*)(vb + ((size_t)((t0 + r) * 4 + b)) * 1024 + h * 64 + pc * 8);
#pragma unroll
      for (int e = 0; e < 8; ++e)
        Lt[(pc * 8 + e) * 136 + r] = (unsigned short)val[e];
    }
    __syncthreads();
#pragma unroll
    for (int cc = 0; cc < 4; ++cc) {
      const int idx = tid + cc * 256;
      const int d = idx >> 4, tc = idx & 15;
      short8 v2 = *(short8*)&Lt[d * 136 + tc * 8];
      *(short8*)(vT + ((size_t)((b * 16 + h) * 64 + d)) * 1024 + t0 + tc * 8) = v2;
    }
  } else {
    const int i = (bid - 512) * 256 + tid;
    if (i < 65536) {
      const int b = i >> 14, h = (i >> 10) & 15, s = i & 1023;
      const unsigned short* kr = kb + ((size_t)(s * 4 + b)) * 1024 + h * 64;
      const float* ur = pbu + h * 64;
      float sum = 0.f;
#pragma unroll
      for (int c = 0; c < 8; ++c) {
        short8 kv = *(const short8*)(kr + c * 8);
#pragma unroll
        for (int e = 0; e < 8; ++e) sum += bf2f((unsigned short)kv[e]) * ur[c * 8 + e];
      }
      uk[i] = sum;
    } else if (i < 98304) {
      const int j = i - 65536;
      const int idx = j >> 4, h = j & 15;
      const unsigned short* pr = pb + (size_t)idx * 1024 + h * 64;
      const float* vr = pbv + h * 64;
      float sum = 0.f;
#pragma unroll
      for (int c = 0; c < 8; ++c) {
        short8 pv = *(const short8*)(pr + c * 8);
#pragma unroll
        for (int e = 0; e < 8; ++e) sum += bf2f((unsigned short)pv[e]) * vr[c * 8 + e];
      }
      vp[(idx << 4) + h] = sum;
    }
  }
}

// ---------------------------------------------------------------------------
// Fused rel-pos MFMA attention (r7/r9 best, ~125 µs): BDW 148 conflict-free
// BD writes; exact-fit 40960 B LDS; merged Phase-3; 4 __syncthreads/iter,
// s-step 128. Attn micro-surgery concluded (r6/r8 A/Bs regressed).
// ---------------------------------------------------------------------------
#define BDW 148  // BDs row stride in floats

__global__ __launch_bounds__(256) void attn_kernel(
    const unsigned short* __restrict__ qb, const unsigned short* __restrict__ kb,
    const unsigned short* __restrict__ pb, const unsigned short* __restrict__ vT,
    const float* __restrict__ uk, const float* __restrict__ vp,
    unsigned short* __restrict__ xb)
{
  // 10240 floats = 40960 B exactly (4 blocks/CU).
  __shared__ __align__(16) float SMEM_ALL[10240];
  float* BDf  = SMEM_ALL;                 // [64][BDW] fp32 (Phases 1-2)
  unsigned short* Pb = (unsigned short*)SMEM_ALL;  // [64][136] bf16 (Phases 4-5)
  float* uk_s  = SMEM_ALL + 9472;         // 128
  float* vp_w  = SMEM_ALL + 9600;         // 192
  float* pmax0 = SMEM_ALL + 9792;         // 64
  float* pmax1 = SMEM_ALL + 9856;         // 64
  float* psum0 = SMEM_ALL + 9920;         // 64
  float* psum1 = SMEM_ALL + 9984;         // 64
  float* m_rowA = SMEM_ALL + 10048;       // 64 (ping)
  float* m_rowB = SMEM_ALL + 10112;       // 64 (pong)
  float* l_row  = SMEM_ALL + 10176;       // 64

  const int tid = threadIdx.x;
  const int lane = tid & 63;
  const int w = tid >> 6;
  const int l15 = lane & 15, quad = lane >> 4;
  const int th = w & 1, sh = w >> 1;

  // XCD swizzle: cluster the 16 q-tiles of one (b,h) on one XCD.
  const int flat = blockIdx.x + (blockIdx.y << 4) + (blockIdx.z << 8);
  const int x8 = flat & 7, s8 = flat >> 3;
  const int hb = x8 * 8 + (s8 >> 4);
  const int t0 = (s8 & 15) * 64;
  const int b = hb >> 4, h = hb & 15;

  // Q as MFMA B-operand: B[k=d][n=t], lane n=l15, k=quad*8+j. qf[ttile][kstep]
  short8 qf[2][2];
#pragma unroll
  for (int tt = 0; tt < 2; ++tt)
#pragma unroll
    for (int kk = 0; kk < 2; ++kk) {
      const int t = t0 + th * 32 + tt * 16 + l15;
      qf[tt][kk] = *(const short8*)(qb + ((size_t)(t * 4 + b)) * 1024 + h * 64 + kk * 32 + quad * 8);
    }

  floatx4 of[2][2];  // O[t-tile][d-tile], rows t=quad*4+reg, cols d=l15
#pragma unroll
  for (int i = 0; i < 2; ++i)
#pragma unroll
    for (int j = 0; j < 2; ++j) of[i][j] = (floatx4){0.f, 0.f, 0.f, 0.f};

  if (tid < 64) { m_rowA[tid] = -3.0e38f; l_row[tid] = 0.f; }
  __syncthreads();

  // per-wave fragment pointers (depend only on s0; same lane pattern each iter)
  const unsigned short* kbase = kb + ((size_t)((sh * 64 + l15) * 4 + b)) * 1024 + h * 64;
  const unsigned short* pbase0 = pb + ((size_t)(sh * 96 + l15)) * 1024 + h * 64;

  // prefetched fragments for the CURRENT iteration
  short8 kf[4][2], pf[6][2];
  {
    const int w0 = 0 - t0 + 960;
#pragma unroll
    for (int st4 = 0; st4 < 4; ++st4) {
      const unsigned short* kr = kbase + (size_t)(st4 * 16) * 4096;
      kf[st4][0] = *(const short8*)(kr + quad * 8);
      kf[st4][1] = *(const short8*)(kr + 32 + quad * 8);
    }
#pragma unroll
    for (int jt = 0; jt < 6; ++jt) {
      const int sA = sh * 96 + jt * 16 + th * 32;  // ssum at tt=0 (s0-independent)
      if (sA <= 16 || sA > 190) continue;          // pf[jt] never consumed
      const unsigned short* pr = pbase0 + (size_t)(w0 + jt * 16) * 1024;
      pf[jt][0] = *(const short8*)(pr + quad * 8);
      pf[jt][1] = *(const short8*)(pr + 32 + quad * 8);
    }
  }

  for (int s0 = 0; s0 < 1024; s0 += 128) {
    const int w0 = s0 - t0 + 960;
    const int par = (s0 >> 7) & 1;
    float* m_prev = par ? m_rowB : m_rowA;
    float* m_next = par ? m_rowA : m_rowB;

    if (tid < 128) uk_s[tid] = uk[((b * 16 + h) << 10) + s0 + tid];
    if (tid < 192) vp_w[tid] = vp[(((size_t)(w0 + tid)) << 4) + h];

    // ---- Phase 1: BD MFMA (prefetched pf) -> one float4/tile + AC MFMA ----
#pragma unroll
    for (int jt = 0; jt < 6; ++jt) {
      const int jjbase = sh * 96 + jt * 16;
#pragma unroll
      for (int tt = 0; tt < 2; ++tt) {
        const int tbase = th * 32 + tt * 16;
        const int ssum = jjbase + tbase;
        // tile's s-range = [ssum-63, ssum-33]; skip if fully outside [0,128)
        if (ssum <= 32 || ssum > 190) continue;   // wave-uniform scalar branch
        floatx4 z = (floatx4){0.f, 0.f, 0.f, 0.f};
        z = MFMA(pf[jt][0], qf[tt][0], z);
        z = MFMA(pf[jt][1], qf[tt][1], z);
        const int tloc = tbase + l15;
        *(float4*)&BDf[tloc * BDW + (ssum - 48) + quad * 4] =
            make_float4(z[0], z[1], z[2], z[3]);
      }
    }

    floatx4 st[4][2];
#pragma unroll
    for (int stile = 0; stile < 4; ++stile) {
#pragma unroll
      for (int tt = 0; tt < 2; ++tt) {
        floatx4 z = (floatx4){0.f, 0.f, 0.f, 0.f};
        z = MFMA(kf[stile][0], qf[tt][0], z);
        z = MFMA(kf[stile][1], qf[tt][1], z);
        st[stile][tt] = z;
      }
    }

    // ---- issue next-iteration K/P fragment loads (in flight across barriers) ----
    {
      const int s0n = (s0 + 128 < 1024) ? (s0 + 128) : 0;  // last iter: dummy reload
      const int w0n = s0n - t0 + 960;
#pragma unroll
      for (int st4 = 0; st4 < 4; ++st4) {
        const unsigned short* kr = kbase + (size_t)(s0n + st4 * 16) * 4096;
        kf[st4][0] = *(const short8*)(kr + quad * 8);
        kf[st4][1] = *(const short8*)(kr + 32 + quad * 8);
      }
#pragma unroll
      for (int jt = 0; jt < 6; ++jt) {
        const int sA = sh * 96 + jt * 16 + th * 32;
        if (sA <= 16 || sA > 190) continue;      // pf[jt] never consumed
        const unsigned short* pr = pbase0 + (size_t)(w0n + jt * 16) * 1024;
        pf[jt][0] = *(const short8*)(pr + quad * 8);
        pf[jt][1] = *(const short8*)(pr + 32 + quad * 8);
      }
    }
    __syncthreads();  // B_a: BDs visible

    // ---- Phase 2: assemble scores + per-t local max ----
    float lmax[2] = {-3.0e38f, -3.0e38f};
#pragma unroll
    for (int stile = 0; stile < 4; ++stile)
#pragma unroll
      for (int tt = 0; tt < 2; ++tt) {
        const int tloc = th * 32 + tt * 16 + l15;
#pragma unroll
        for (int reg = 0; reg < 4; ++reg) {
          const int sloc = sh * 64 + stile * 16 + quad * 4 + reg;
          const int jj = sloc - tloc + 63;
          float v = 0.125f * (st[stile][tt][reg] + BDf[tloc * BDW + sloc - l15 + 15] +
                              uk_s[sloc] + vp_w[jj]);
          st[stile][tt][reg] = v;
          lmax[tt] = fmaxf(lmax[tt], v);
        }
      }
#pragma unroll
    for (int tt = 0; tt < 2; ++tt) {
      lmax[tt] = fmaxf(lmax[tt], __shfl_xor(lmax[tt], 16));
      lmax[tt] = fmaxf(lmax[tt], __shfl_xor(lmax[tt], 32));
    }
    if (quad == 0) {
      float* pm = sh ? pmax1 : pmax0;
      pm[th * 32 + l15] = lmax[0];
      pm[th * 32 + 16 + l15] = lmax[1];
    }
    __syncthreads();  // B_b: BDs reads done; pmax visible

    // ---- Phase 3 (merged): per-thread redundant m/alpha from pmax+m_prev ----
    float mn_keep = 0.f;
    if (tid < 64) {
      const float mo = m_prev[tid];
      mn_keep = fmaxf(mo, fmaxf(pmax0[tid], pmax1[tid]));
      m_next[tid] = mn_keep;    // read only next iteration (after its B_b)
    }
    float mt[2];
#pragma unroll
    for (int tt = 0; tt < 2; ++tt) {
      const int r = th * 32 + tt * 16 + l15;
      mt[tt] = fmaxf(m_prev[r], fmaxf(pmax0[r], pmax1[r]));
    }

    // ---- Phase 4: P=exp, Pb write (unions over dead BDs), psum, O rescale ----
    float lsum[2] = {0.f, 0.f};
#pragma unroll
    for (int stile = 0; stile < 4; ++stile)
#pragma unroll
      for (int tt = 0; tt < 2; ++tt) {
        float p0 = __expf(st[stile][tt][0] - mt[tt]);
        float p1 = __expf(st[stile][tt][1] - mt[tt]);
        float p2 = __expf(st[stile][tt][2] - mt[tt]);
        float p3 = __expf(st[stile][tt][3] - mt[tt]);
        lsum[tt] += p0 + p1 + p2 + p3;
        const int tloc = th * 32 + tt * 16 + l15;
        const int sb = sh * 64 + stile * 16 + quad * 4;
        ushort4v pk = (ushort4v){f2bf(p0), f2bf(p1), f2bf(p2), f2bf(p3)};
        *(ushort4v*)&Pb[tloc * 136 + sb] = pk;
      }
#pragma unroll
    for (int tt = 0; tt < 2; ++tt) {
      lsum[tt] += __shfl_xor(lsum[tt], 16);
      lsum[tt] += __shfl_xor(lsum[tt], 32);
    }
    if (quad == 0) {
      float* ps = sh ? psum1 : psum0;
      ps[th * 32 + l15] = lsum[0];
      ps[th * 32 + 16 + l15] = lsum[1];
    }
    // O rescale: alpha recomputed per-thread (float4 reads, 8 expf)
#pragma unroll
    for (int tt = 0; tt < 2; ++tt) {
      const int base = th * 32 + tt * 16 + quad * 4;
      const float4 mo4 = *(const float4*)&m_prev[base];
      const float4 p04 = *(const float4*)&pmax0[base];
      const float4 p14 = *(const float4*)&pmax1[base];
#pragma unroll
      for (int reg = 0; reg < 4; ++reg) {
        const float mo = ((const float*)&mo4)[reg];
        const float mn = fmaxf(mo, fmaxf(((const float*)&p04)[reg],
                                         ((const float*)&p14)[reg]));
        const float ar = __expf(mo - mn);
        of[tt][0][reg] *= ar;
        of[tt][1][reg] *= ar;
      }
    }
    __syncthreads();  // B_d: Pb + psum visible

    // ---- Phase 5: l update + PV MFMA (V loads here) ----
    if (tid < 64) {
      const float alpha = __expf(m_prev[tid] - mn_keep);
      l_row[tid] = l_row[tid] * alpha + psum0[tid] + psum1[tid];
    }
#pragma unroll
    for (int kk2 = 0; kk2 < 4; ++kk2) {
      short8 pa[2], vf[2];
#pragma unroll
      for (int tt = 0; tt < 2; ++tt)
        pa[tt] = *(short8*)&Pb[(th * 32 + tt * 16 + l15) * 136 + kk2 * 32 + quad * 8];
#pragma unroll
      for (int dt = 0; dt < 2; ++dt)
        vf[dt] = *(const short8*)(vT + ((size_t)((b * 16 + h) * 64 + sh * 32 + dt * 16 + l15)) * 1024 +
                                  s0 + kk2 * 32 + quad * 8);
#pragma unroll
      for (int tt = 0; tt < 2; ++tt)
#pragma unroll
        for (int dt = 0; dt < 2; ++dt)
          of[tt][dt] = MFMA(pa[tt], vf[dt], of[tt][dt]);
    }
    __syncthreads();  // B_e: Pb reads done before next-iter BDs writes
  }

#pragma unroll
  for (int tt = 0; tt < 2; ++tt)
#pragma unroll
    for (int reg = 0; reg < 4; ++reg) {
      const int t = th * 32 + tt * 16 + quad * 4 + reg;
      const float il = 1.f / l_row[t];
#pragma unroll
      for (int dt = 0; dt < 2; ++dt) {
        const int d = sh * 32 + dt * 16 + l15;
        xb[((size_t)((t0 + t) * 4 + b)) * 1024 + h * 64 + d] = f2bf(of[tt][dt][reg] * il);
      }
    }
}

// ---------------------------------------------------------------------------
extern "C" void kernel_launch(void* const* d_in, const int* in_sizes, int n_in,
                              void* d_out, int out_size, void* d_ws, size_t ws_size,
                              hipStream_t stream) {
  const float* query   = (const float*)d_in[0];
  const float* key_    = (const float*)d_in[1];
  const float* value   = (const float*)d_in[2];
  const float* pos_emb = (const float*)d_in[3];
  const float* Wq  = (const float*)d_in[4];
  const float* bq  = (const float*)d_in[5];
  const float* Wk  = (const float*)d_in[6];
  const float* bk  = (const float*)d_in[7];
  const float* Wv  = (const float*)d_in[8];
  const float* bv  = (const float*)d_in[9];
  const float* Wp  = (const float*)d_in[10];
  const float* Wo  = (const float*)d_in[11];
  const float* bo  = (const float*)d_in[12];
  const float* pbu = (const float*)d_in[13];
  const float* pbv = (const float*)d_in[14];
  float* out = (float*)d_out;

  // workspace (ushort elements), ~69.6 MB total
  unsigned short* U = (unsigned short*)d_ws;
  unsigned short* qin = U;                   // bf16 query   (later: attn out xb)
  unsigned short* kin = U + 4194304;         // bf16 key
  unsigned short* vin = U + 8388608;         // bf16 value
  unsigned short* pe  = U + 12582912;        // bf16 pos_emb 2048 rows (later: vTb)
  unsigned short* wq  = U + 14680064;
  unsigned short* wk  = U + 15728640;
  unsigned short* wv  = U + 16777216;
  unsigned short* wp  = U + 17825792;
  unsigned short* wo  = U + 18874368;
  unsigned short* qb  = U + 19922944;        // Q proj
  unsigned short* kb  = U + 24117248;        // K proj
  unsigned short* pb  = U + 28311552;        // P proj
  unsigned short* vpo = U + 30408704;        // V proj
  unsigned short* vTb = pe;                  // aliases pe+wq+wk (dead after projections)
  unsigned short* xb  = qin;                 // attn out (qin dead after projections)
  float* fbase = (float*)(U + 34603008);
  float* uk = fbase;                         // 65536 floats
  float* vp = fbase + 65536;                 // 32768 floats

  const dim3 blk(256);
  const dim3 blk512(512);

  // 1. convert everything to bf16 (one HBM-bound pass)
  convert_kernel<<<dim3(9728), blk, 0, stream>>>(
      query, key_, value, pos_emb, Wq, Wk, Wv, Wp, Wo,
      qin, kin, vin, pe, wq, wk, wv, wp, wo);

  // 2. fused Q,K,V,P projections, depth-2 pipelined, 8-wave blocks
  GemmJobs jobs;
  jobs.j[0] = GemmJob{qin, wq, bq, qb, 32};
  jobs.j[1] = GemmJob{kin, wk, bk, kb, 32};
  jobs.j[2] = GemmJob{vin, wv, bv, vpo, 32};
  jobs.j[3] = GemmJob{pe,  wp, nullptr, pb, 16};
  gemm_qkvp<<<dim3(8, 32, 4), blk512, 0, stream>>>(jobs);

  // 3. fused transpose V + rank-1 bias dots (one launch)
  transpose_precompute<<<dim3(896), blk, 0, stream>>>(
      vpo, vTb, kb, pb, pbu, pbv, uk, vp);

  // 4. fused attention (writes into dead qin buffer)
  attn_kernel<<<dim3(16, 16, 4), blk, 0, stream>>>(qb, kb, pb, vTb, uk, vp, xb);

  // 5. output projection -> fp32 d_out, depth-2 pipelined (4-wave core)
  gemm_one<0><<<dim3(8, 32), blk, 0, stream>>>(xb, wo, bo, out);
}

// Round 11
// 315.928 us; speedup vs baseline: 1.1628x; 1.0045x over previous
//
#include <hip/hip_runtime.h>
#include <hip/hip_bf16.h>
#include <math.h>

// Problem: T=1024, B=4, H=16, D=64, C=1024.
#define T_SEQ 1024
#define NB 4
#define NH 16
#define DD 64
#define CC 1024

typedef __attribute__((ext_vector_type(8))) short short8;   // 8 x bf16 (4 VGPR)
typedef __attribute__((ext_vector_type(4))) float floatx4;  // MFMA C/D
typedef __attribute__((ext_vector_type(4))) unsigned short ushort4v;

#define MFMA(a, b, c) __builtin_amdgcn_mfma_f32_16x16x32_bf16((a), (b), (c), 0, 0, 0)

__device__ inline float bf2f(unsigned short u) {
  union { unsigned int i; float f; } c; c.i = ((unsigned int)u) << 16; return c.f;
}
__device__ inline unsigned short f2bf(float x) {
  union { float f; unsigned int i; } c; c.f = x;
  unsigned int u = c.i;
  u += 0x7fff + ((u >> 16) & 1);   // RNE (inputs are finite)
  return (unsigned short)(u >> 16);
}

// async global->LDS, 16B per lane; LDS dest = wave-uniform base + lane*16
__device__ __forceinline__ void gload_lds16(const void* g, void* l) {
  __builtin_amdgcn_global_load_lds(
      (const __attribute__((address_space(1))) unsigned int*)g,
      (__attribute__((address_space(3))) unsigned int*)l, 16, 0, 0);
}

// ---------------------------------------------------------------------------
// Convert pass: fp32 -> bf16 for q/k/v inputs, pos_emb (padded to 2048 rows),
// and the 5 weight matrices. One vec8 per thread.
// ---------------------------------------------------------------------------
__global__ __launch_bounds__(256) void convert_kernel(
    const float* __restrict__ q, const float* __restrict__ k,
    const float* __restrict__ v, const float* __restrict__ pe_in,
    const float* __restrict__ wq, const float* __restrict__ wk,
    const float* __restrict__ wv, const float* __restrict__ wp,
    const float* __restrict__ wo,
    unsigned short* __restrict__ qo, unsigned short* __restrict__ ko,
    unsigned short* __restrict__ vo, unsigned short* __restrict__ po,
    unsigned short* __restrict__ wqo, unsigned short* __restrict__ wko,
    unsigned short* __restrict__ wvo, unsigned short* __restrict__ wpo,
    unsigned short* __restrict__ woo)
{
  const int i = blockIdx.x * 256 + threadIdx.x;  // vec8 index
  const float* src; unsigned short* dst; int off;
  if      (i < 524288)  { src = q;     dst = qo;  off = i; }
  else if (i < 1048576) { src = k;     dst = ko;  off = i - 524288; }
  else if (i < 1572864) { src = v;     dst = vo;  off = i - 1048576; }
  else if (i < 1834880) { src = pe_in; dst = po;  off = i - 1572864; }
  else if (i < 1965952) { src = wq;    dst = wqo; off = i - 1834880; }
  else if (i < 2097024) { src = wk;    dst = wko; off = i - 1965952; }
  else if (i < 2228096) { src = wv;    dst = wvo; off = i - 2097024; }
  else if (i < 2359168) { src = wp;    dst = wpo; off = i - 2228096; }
  else if (i < 2490240) { src = wo;    dst = woo; off = i - 2359168; }
  else {  // zero-fill pos_emb pad row 2047 (128 vec8 = 1024 elems)
    const int j = i - 2490240;
    *(short8*)&po[2047 * 1024 + j * 8] = (short8){0, 0, 0, 0, 0, 0, 0, 0};
    return;
  }
  const float4 a0 = *(const float4*)(src + (size_t)off * 8);
  const float4 a1 = *(const float4*)(src + (size_t)off * 8 + 4);
  short8 val = (short8){(short)f2bf(a0.x), (short)f2bf(a0.y), (short)f2bf(a0.z), (short)f2bf(a0.w),
                        (short)f2bf(a1.x), (short)f2bf(a1.y), (short)f2bf(a1.z), (short)f2bf(a1.w)};
  *(short8*)&dst[(size_t)off * 8] = val;
}

// ---------------------------------------------------------------------------
// Depth-2 pipelined GEMM core, 8-wave (512-thread), 3-BUFFER rotation:
// LDS 48 KB (3 x (8KB A + 8KB B)) -> 3 blocks/CU (was 2 at 64 KB), cutting
// gemm_qkvp's residency rounds 896/(256*2)=2 -> 896/(256*3)=1.17.
// Order per step t: WAITBAR(vmcnt 2) -> STAGE(t+2) -> COMPUTE(t).
//   * wait drains this wave's stage(t) (4 loads outstanding, oldest 2);
//     barrier then publishes ALL waves' stage(t) (each waited before it).
//   * stage(t+2) targets buf[(t+2)%3] = buf[(t-1)%3], read by compute(t-1),
//     which every wave finished before the barrier just crossed -> race-free.
// sched_barrier(0) after s_barrier pins the ds_reads of COMPUTE below it.
// C[m,n] = sum_k A[m,k]*W[n,k] (+bias[n]).  Requires K=1024 here
// ((K/32-2) % 3 == 0).
// ---------------------------------------------------------------------------
template <int OUT_BF16>
__device__ __forceinline__ void gemm_core_p8(
    const unsigned short* __restrict__ A, const unsigned short* __restrict__ Wt,
    const float* __restrict__ bias, void* __restrict__ Cv,
    unsigned short* SM, int N, int K, int bm, int bn)
{
  const int tid = threadIdx.x;
  const int lane = tid & 63;
  const int w = tid >> 6;                 // 0..7
  const int l15 = lane & 15, quad = lane >> 4;
  const int rw = (w >> 2) * 64, cw = (w & 3) * 32;

  floatx4 acc[4][2];
#pragma unroll
  for (int i = 0; i < 4; ++i)
#pragma unroll
    for (int j = 0; j < 2; ++j) acc[i][j] = (floatx4){0.f, 0.f, 0.f, 0.f};

  const int lrow = lane >> 2, lcol = (lane & 3) * 8;  // 4 lanes per row
  const unsigned short* Ag = A + (size_t)(bm + w * 16 + lrow) * K + lcol;
  const unsigned short* Wg = Wt + (size_t)(bn + w * 16 + lrow) * K + lcol;

#define ASX(i) (SM + (i) * 4096)
#define BSX(i) (SM + 12288 + (i) * 4096)

#define G_STAGE(i, KOFF)                                \
  do {                                                  \
    gload_lds16(Ag + (KOFF), ASX(i) + w * 512);         \
    gload_lds16(Wg + (KOFF), BSX(i) + w * 512);         \
  } while (0)

#define G_WAITBAR(NN)                                   \
  do {                                                  \
    asm volatile("s_waitcnt vmcnt(" #NN ")" ::: "memory"); \
    __builtin_amdgcn_s_barrier();                       \
    __builtin_amdgcn_sched_barrier(0);                  \
  } while (0)

#define G_COMPUTE(bi)                                                    \
  do {                                                                   \
    short8 af[4], bfr[2];                                                \
    _Pragma("unroll")                                                    \
    for (int i = 0; i < 4; ++i)                                          \
      af[i] = *(short8*)&(ASX(bi))[(rw + i * 16 + l15) * 32 + quad * 8]; \
    _Pragma("unroll")                                                    \
    for (int j = 0; j < 2; ++j)                                          \
      bfr[j] = *(short8*)&(BSX(bi))[(cw + j * 16 + l15) * 32 + quad * 8];\
    _Pragma("unroll")                                                    \
    for (int i = 0; i < 4; ++i)                                          \
      _Pragma("unroll")                                                  \
      for (int j = 0; j < 2; ++j)                                        \
        acc[i][j] = MFMA(af[i], bfr[j], acc[i][j]);                      \
  } while (0)

  // prologue: stages 0 and 1 in flight (2 loads each)
  G_STAGE(0, 0);
  G_STAGE(1, 32);

  // 30 pipelined steps (t = 0..29), then 2 drain steps. buf = step % 3.
  for (int t = 0; t < K / 32 - 2; t += 3) {
    G_WAITBAR(2); G_STAGE(2, (t + 2) * 32); G_COMPUTE(0);
    G_WAITBAR(2); G_STAGE(0, (t + 3) * 32); G_COMPUTE(1);
    G_WAITBAR(2); G_STAGE(1, (t + 4) * 32); G_COMPUTE(2);
  }
  G_WAITBAR(2); G_COMPUTE(0);   // step K/32-2 (buf 0)
  G_WAITBAR(0); G_COMPUTE(1);   // step K/32-1 (buf 1)

#undef G_STAGE
#undef G_WAITBAR
#undef G_COMPUTE
#undef ASX
#undef BSX

#pragma unroll
  for (int j = 0; j < 2; ++j) {
    const int col = bn + cw + j * 16 + l15;
    const float bj = bias ? bias[col] : 0.f;
#pragma unroll
    for (int i = 0; i < 4; ++i) {
      const int row0 = bm + rw + i * 16 + quad * 4;
#pragma unroll
      for (int reg = 0; reg < 4; ++reg) {
        const float v = acc[i][j][reg] + bj;
        if (OUT_BF16)
          ((unsigned short*)Cv)[(size_t)(row0 + reg) * N + col] = f2bf(v);
        else
          ((float*)Cv)[(size_t)(row0 + reg) * N + col] = v;
      }
    }
  }
}

struct GemmJob { const unsigned short* A; const unsigned short* Wt;
                 const float* bias; unsigned short* C; int mtiles; };
struct GemmJobs { GemmJob j[4]; };

// Fused Q,K,V,P projection GEMMs (z picks job; P has 16 m-tiles). 512 thr.
__global__ __launch_bounds__(512) void gemm_qkvp(GemmJobs jobs) {
  __shared__ __align__(16) unsigned short SM[6 * 4096];  // 48 KB
  GemmJob jb = jobs.j[blockIdx.z];
  if ((int)blockIdx.y >= jb.mtiles) return;
  gemm_core_p8<1>(jb.A, jb.Wt, jb.bias, jb.C, SM, 1024, 1024,
                  blockIdx.y * 128, blockIdx.x * 128);
}

// gemm_one: 256 blocks = 1 block/CU; old 256-thread core gave only
// 1 wave/SIMD (zero latency cover at each s_waitcnt). 8-wave core -> 2/SIMD.
template <int OUT_BF16>
__global__ __launch_bounds__(512) void gemm_one(
    const unsigned short* __restrict__ A, const unsigned short* __restrict__ Wt,
    const float* __restrict__ bias, void* __restrict__ Cv) {
  __shared__ __align__(16) unsigned short SM[6 * 4096];  // 48 KB
  gemm_core_p8<OUT_BF16>(A, Wt, bias, Cv, SM, 1024, 1024,
                         blockIdx.y * 128, blockIdx.x * 128);
}

// ---------------------------------------------------------------------------
// Fused: transpose V (blocks 0..511) + rank-1 bias dots (blocks 512..895).
// ---------------------------------------------------------------------------
__global__ __launch_bounds__(256) void transpose_precompute(
    const unsigned short* __restrict__ vb, unsigned short* __restrict__ vT,
    const unsigned short* __restrict__ kb, const unsigned short* __restrict__ pb,
    const float* __restrict__ pbu, const float* __restrict__ pbv,
    float* __restrict__ uk, float* __restrict__ vp)
{
  __shared__ __align__(16) unsigned short Lt[64 * 136];
  const int bid = blockIdx.x;
  const int tid = threadIdx.x;
  if (bid < 512) {
    const int t0 = (bid & 7) * 128;
    const int h = (bid >> 3) & 15, b = bid >> 7;
#pragma unroll
    for (int cc = 0; cc < 4; ++cc) {
      const int idx = tid + cc * 256;
      const int r = idx >> 3, pc = idx & 7;
      short8 val = *(const short8*)(vb + ((size_t)((t0 + r) * 4 + b)) * 1024 + h * 64 + pc * 8);
#pragma unroll
      for (int e = 0; e < 8; ++e)
        Lt[(pc * 8 + e) * 136 + r] = (unsigned short)val[e];
    }
    __syncthreads();
#pragma unroll
    for (int cc = 0; cc < 4; ++cc) {
      const int idx = tid + cc * 256;
      const int d = idx >> 4, tc = idx & 15;
      short8 v2 = *(short8*)&Lt[d * 136 + tc * 8];
      *(short8*)(vT + ((size_t)((b * 16 + h) * 64 + d)) * 1024 + t0 + tc * 8) = v2;
    }
  } else {
    const int i = (bid - 512) * 256 + tid;
    if (i < 65536) {
      const int b = i >> 14, h = (i >> 10) & 15, s = i & 1023;
      const unsigned short* kr = kb + ((size_t)(s * 4 + b)) * 1024 + h * 64;
      const float* ur = pbu + h * 64;
      float sum = 0.f;
#pragma unroll
      for (int c = 0; c < 8; ++c) {
        short8 kv = *(const short8*)(kr + c * 8);
#pragma unroll
        for (int e = 0; e < 8; ++e) sum += bf2f((unsigned short)kv[e]) * ur[c * 8 + e];
      }
      uk[i] = sum;
    } else if (i < 98304) {
      const int j = i - 65536;
      const int idx = j >> 4, h = j & 15;
      const unsigned short* pr = pb + (size_t)idx * 1024 + h * 64;
      const float* vr = pbv + h * 64;
      float sum = 0.f;
#pragma unroll
      for (int c = 0; c < 8; ++c) {
        short8 pv = *(const short8*)(pr + c * 8);
#pragma unroll
        for (int e = 0; e < 8; ++e) sum += bf2f((unsigned short)pv[e]) * vr[c * 8 + e];
      }
      vp[(idx << 4) + h] = sum;
    }
  }
}

// ---------------------------------------------------------------------------
// Fused rel-pos MFMA attention (r7/r9 best, ~125-130 µs): BDW 148
// conflict-free BD writes; exact-fit 40960 B LDS; merged Phase-3;
// 4 __syncthreads/iter, s-step 128. Attn micro-surgery concluded
// (r6/r8 A/Bs regressed).
// ---------------------------------------------------------------------------
#define BDW 148  // BDs row stride in floats

__global__ __launch_bounds__(256) void attn_kernel(
    const unsigned short* __restrict__ qb, const unsigned short* __restrict__ kb,
    const unsigned short* __restrict__ pb, const unsigned short* __restrict__ vT,
    const float* __restrict__ uk, const float* __restrict__ vp,
    unsigned short* __restrict__ xb)
{
  // 10240 floats = 40960 B exactly (4 blocks/CU).
  __shared__ __align__(16) float SMEM_ALL[10240];
  float* BDf  = SMEM_ALL;                 // [64][BDW] fp32 (Phases 1-2)
  unsigned short* Pb = (unsigned short*)SMEM_ALL;  // [64][136] bf16 (Phases 4-5)
  float* uk_s  = SMEM_ALL + 9472;         // 128
  float* vp_w  = SMEM_ALL + 9600;         // 192
  float* pmax0 = SMEM_ALL + 9792;         // 64
  float* pmax1 = SMEM_ALL + 9856;         // 64
  float* psum0 = SMEM_ALL + 9920;         // 64
  float* psum1 = SMEM_ALL + 9984;         // 64
  float* m_rowA = SMEM_ALL + 10048;       // 64 (ping)
  float* m_rowB = SMEM_ALL + 10112;       // 64 (pong)
  float* l_row  = SMEM_ALL + 10176;       // 64

  const int tid = threadIdx.x;
  const int lane = tid & 63;
  const int w = tid >> 6;
  const int l15 = lane & 15, quad = lane >> 4;
  const int th = w & 1, sh = w >> 1;

  // XCD swizzle: cluster the 16 q-tiles of one (b,h) on one XCD.
  const int flat = blockIdx.x + (blockIdx.y << 4) + (blockIdx.z << 8);
  const int x8 = flat & 7, s8 = flat >> 3;
  const int hb = x8 * 8 + (s8 >> 4);
  const int t0 = (s8 & 15) * 64;
  const int b = hb >> 4, h = hb & 15;

  // Q as MFMA B-operand: B[k=d][n=t], lane n=l15, k=quad*8+j. qf[ttile][kstep]
  short8 qf[2][2];
#pragma unroll
  for (int tt = 0; tt < 2; ++tt)
#pragma unroll
    for (int kk = 0; kk < 2; ++kk) {
      const int t = t0 + th * 32 + tt * 16 + l15;
      qf[tt][kk] = *(const short8*)(qb + ((size_t)(t * 4 + b)) * 1024 + h * 64 + kk * 32 + quad * 8);
    }

  floatx4 of[2][2];  // O[t-tile][d-tile], rows t=quad*4+reg, cols d=l15
#pragma unroll
  for (int i = 0; i < 2; ++i)
#pragma unroll
    for (int j = 0; j < 2; ++j) of[i][j] = (floatx4){0.f, 0.f, 0.f, 0.f};

  if (tid < 64) { m_rowA[tid] = -3.0e38f; l_row[tid] = 0.f; }
  __syncthreads();

  // per-wave fragment pointers (depend only on s0; same lane pattern each iter)
  const unsigned short* kbase = kb + ((size_t)((sh * 64 + l15) * 4 + b)) * 1024 + h * 64;
  const unsigned short* pbase0 = pb + ((size_t)(sh * 96 + l15)) * 1024 + h * 64;

  // prefetched fragments for the CURRENT iteration
  short8 kf[4][2], pf[6][2];
  {
    const int w0 = 0 - t0 + 960;
#pragma unroll
    for (int st4 = 0; st4 < 4; ++st4) {
      const unsigned short* kr = kbase + (size_t)(st4 * 16) * 4096;
      kf[st4][0] = *(const short8*)(kr + quad * 8);
      kf[st4][1] = *(const short8*)(kr + 32 + quad * 8);
    }
#pragma unroll
    for (int jt = 0; jt < 6; ++jt) {
      const int sA = sh * 96 + jt * 16 + th * 32;  // ssum at tt=0 (s0-independent)
      if (sA <= 16 || sA > 190) continue;          // pf[jt] never consumed
      const unsigned short* pr = pbase0 + (size_t)(w0 + jt * 16) * 1024;
      pf[jt][0] = *(const short8*)(pr + quad * 8);
      pf[jt][1] = *(const short8*)(pr + 32 + quad * 8);
    }
  }

  for (int s0 = 0; s0 < 1024; s0 += 128) {
    const int w0 = s0 - t0 + 960;
    const int par = (s0 >> 7) & 1;
    float* m_prev = par ? m_rowB : m_rowA;
    float* m_next = par ? m_rowA : m_rowB;

    if (tid < 128) uk_s[tid] = uk[((b * 16 + h) << 10) + s0 + tid];
    if (tid < 192) vp_w[tid] = vp[(((size_t)(w0 + tid)) << 4) + h];

    // ---- Phase 1: BD MFMA (prefetched pf) -> one float4/tile + AC MFMA ----
#pragma unroll
    for (int jt = 0; jt < 6; ++jt) {
      const int jjbase = sh * 96 + jt * 16;
#pragma unroll
      for (int tt = 0; tt < 2; ++tt) {
        const int tbase = th * 32 + tt * 16;
        const int ssum = jjbase + tbase;
        // tile's s-range = [ssum-63, ssum-33]; skip if fully outside [0,128)
        if (ssum <= 32 || ssum > 190) continue;   // wave-uniform scalar branch
        floatx4 z = (floatx4){0.f, 0.f, 0.f, 0.f};
        z = MFMA(pf[jt][0], qf[tt][0], z);
        z = MFMA(pf[jt][1], qf[tt][1], z);
        const int tloc = tbase + l15;
        *(float4*)&BDf[tloc * BDW + (ssum - 48) + quad * 4] =
            make_float4(z[0], z[1], z[2], z[3]);
      }
    }

    floatx4 st[4][2];
#pragma unroll
    for (int stile = 0; stile < 4; ++stile) {
#pragma unroll
      for (int tt = 0; tt < 2; ++tt) {
        floatx4 z = (floatx4){0.f, 0.f, 0.f, 0.f};
        z = MFMA(kf[stile][0], qf[tt][0], z);
        z = MFMA(kf[stile][1], qf[tt][1], z);
        st[stile][tt] = z;
      }
    }

    // ---- issue next-iteration K/P fragment loads (in flight across barriers) ----
    {
      const int s0n = (s0 + 128 < 1024) ? (s0 + 128) : 0;  // last iter: dummy reload
      const int w0n = s0n - t0 + 960;
#pragma unroll
      for (int st4 = 0; st4 < 4; ++st4) {
        const unsigned short* kr = kbase + (size_t)(s0n + st4 * 16) * 4096;
        kf[st4][0] = *(const short8*)(kr + quad * 8);
        kf[st4][1] = *(const short8*)(kr + 32 + quad * 8);
      }
#pragma unroll
      for (int jt = 0; jt < 6; ++jt) {
        const int sA = sh * 96 + jt * 16 + th * 32;
        if (sA <= 16 || sA > 190) continue;      // pf[jt] never consumed
        const unsigned short* pr = pbase0 + (size_t)(w0n + jt * 16) * 1024;
        pf[jt][0] = *(const short8*)(pr + quad * 8);
        pf[jt][1] = *(const short8*)(pr + 32 + quad * 8);
      }
    }
    __syncthreads();  // B_a: BDs visible

    // ---- Phase 2: assemble scores + per-t local max ----
    float lmax[2] = {-3.0e38f, -3.0e38f};
#pragma unroll
    for (int stile = 0; stile < 4; ++stile)
#pragma unroll
      for (int tt = 0; tt < 2; ++tt) {
        const int tloc = th * 32 + tt * 16 + l15;
#pragma unroll
        for (int reg = 0; reg < 4; ++reg) {
          const int sloc = sh * 64 + stile * 16 + quad * 4 + reg;
          const int jj = sloc - tloc + 63;
          float v = 0.125f * (st[stile][tt][reg] + BDf[tloc * BDW + sloc - l15 + 15] +
                              uk_s[sloc] + vp_w[jj]);
          st[stile][tt][reg] = v;
          lmax[tt] = fmaxf(lmax[tt], v);
        }
      }
#pragma unroll
    for (int tt = 0; tt < 2; ++tt) {
      lmax[tt] = fmaxf(lmax[tt], __shfl_xor(lmax[tt], 16));
      lmax[tt] = fmaxf(lmax[tt], __shfl_xor(lmax[tt], 32));
    }
    if (quad == 0) {
      float* pm = sh ? pmax1 : pmax0;
      pm[th * 32 + l15] = lmax[0];
      pm[th * 32 + 16 + l15] = lmax[1];
    }
    __syncthreads();  // B_b: BDs reads done; pmax visible

    // ---- Phase 3 (merged): per-thread redundant m/alpha from pmax+m_prev ----
    float mn_keep = 0.f;
    if (tid < 64) {
      const float mo = m_prev[tid];
      mn_keep = fmaxf(mo, fmaxf(pmax0[tid], pmax1[tid]));
      m_next[tid] = mn_keep;    // read only next iteration (after its B_b)
    }
    float mt[2];
#pragma unroll
    for (int tt = 0; tt < 2; ++tt) {
      const int r = th * 32 + tt * 16 + l15;
      mt[tt] = fmaxf(m_prev[r], fmaxf(pmax0[r], pmax1[r]));
    }

    // ---- Phase 4: P=exp, Pb write (unions over dead BDs), psum, O rescale ----
    float lsum[2] = {0.f, 0.f};
#pragma unroll
    for (int stile = 0; stile < 4; ++stile)
#pragma unroll
      for (int tt = 0; tt < 2; ++tt) {
        float p0 = __expf(st[stile][tt][0] - mt[tt]);
        float p1 = __expf(st[stile][tt][1] - mt[tt]);
        float p2 = __expf(st[stile][tt][2] - mt[tt]);
        float p3 = __expf(st[stile][tt][3] - mt[tt]);
        lsum[tt] += p0 + p1 + p2 + p3;
        const int tloc = th * 32 + tt * 16 + l15;
        const int sb = sh * 64 + stile * 16 + quad * 4;
        ushort4v pk = (ushort4v){f2bf(p0), f2bf(p1), f2bf(p2), f2bf(p3)};
        *(ushort4v*)&Pb[tloc * 136 + sb] = pk;
      }
#pragma unroll
    for (int tt = 0; tt < 2; ++tt) {
      lsum[tt] += __shfl_xor(lsum[tt], 16);
      lsum[tt] += __shfl_xor(lsum[tt], 32);
    }
    if (quad == 0) {
      float* ps = sh ? psum1 : psum0;
      ps[th * 32 + l15] = lsum[0];
      ps[th * 32 + 16 + l15] = lsum[1];
    }
    // O rescale: alpha recomputed per-thread (float4 reads, 8 expf)
#pragma unroll
    for (int tt = 0; tt < 2; ++tt) {
      const int base = th * 32 + tt * 16 + quad * 4;
      const float4 mo4 = *(const float4*)&m_prev[base];
      const float4 p04 = *(const float4*)&pmax0[base];
      const float4 p14 = *(const float4*)&pmax1[base];
#pragma unroll
      for (int reg = 0; reg < 4; ++reg) {
        const float mo = ((const float*)&mo4)[reg];
        const float mn = fmaxf(mo, fmaxf(((const float*)&p04)[reg],
                                         ((const float*)&p14)[reg]));
        const float ar = __expf(mo - mn);
        of[tt][0][reg] *= ar;
        of[tt][1][reg] *= ar;
      }
    }
    __syncthreads();  // B_d: Pb + psum visible

    // ---- Phase 5: l update + PV MFMA (V loads here) ----
    if (tid < 64) {
      const float alpha = __expf(m_prev[tid] - mn_keep);
      l_row[tid] = l_row[tid] * alpha + psum0[tid] + psum1[tid];
    }
#pragma unroll
    for (int kk2 = 0; kk2 < 4; ++kk2) {
      short8 pa[2], vf[2];
#pragma unroll
      for (int tt = 0; tt < 2; ++tt)
        pa[tt] = *(short8*)&Pb[(th * 32 + tt * 16 + l15) * 136 + kk2 * 32 + quad * 8];
#pragma unroll
      for (int dt = 0; dt < 2; ++dt)
        vf[dt] = *(const short8*)(vT + ((size_t)((b * 16 + h) * 64 + sh * 32 + dt * 16 + l15)) * 1024 +
                                  s0 + kk2 * 32 + quad * 8);
#pragma unroll
      for (int tt = 0; tt < 2; ++tt)
#pragma unroll
        for (int dt = 0; dt < 2; ++dt)
          of[tt][dt] = MFMA(pa[tt], vf[dt], of[tt][dt]);
    }
    __syncthreads();  // B_e: Pb reads done before next-iter BDs writes
  }

#pragma unroll
  for (int tt = 0; tt < 2; ++tt)
#pragma unroll
    for (int reg = 0; reg < 4; ++reg) {
      const int t = th * 32 + tt * 16 + quad * 4 + reg;
      const float il = 1.f / l_row[t];
#pragma unroll
      for (int dt = 0; dt < 2; ++dt) {
        const int d = sh * 32 + dt * 16 + l15;
        xb[((size_t)((t0 + t) * 4 + b)) * 1024 + h * 64 + d] = f2bf(of[tt][dt][reg] * il);
      }
    }
}

// ---------------------------------------------------------------------------
extern "C" void kernel_launch(void* const* d_in, const int* in_sizes, int n_in,
                              void* d_out, int out_size, void* d_ws, size_t ws_size,
                              hipStream_t stream) {
  const float* query   = (const float*)d_in[0];
  const float* key_    = (const float*)d_in[1];
  const float* value   = (const float*)d_in[2];
  const float* pos_emb = (const float*)d_in[3];
  const float* Wq  = (const float*)d_in[4];
  const float* bq  = (const float*)d_in[5];
  const float* Wk  = (const float*)d_in[6];
  const float* bk  = (const float*)d_in[7];
  const float* Wv  = (const float*)d_in[8];
  const float* bv  = (const float*)d_in[9];
  const float* Wp  = (const float*)d_in[10];
  const float* Wo  = (const float*)d_in[11];
  const float* bo  = (const float*)d_in[12];
  const float* pbu = (const float*)d_in[13];
  const float* pbv = (const float*)d_in[14];
  float* out = (float*)d_out;

  // workspace (ushort elements), ~69.6 MB total
  unsigned short* U = (unsigned short*)d_ws;
  unsigned short* qin = U;                   // bf16 query   (later: attn out xb)
  unsigned short* kin = U + 4194304;         // bf16 key
  unsigned short* vin = U + 8388608;         // bf16 value
  unsigned short* pe  = U + 12582912;        // bf16 pos_emb 2048 rows (later: vTb)
  unsigned short* wq  = U + 14680064;
  unsigned short* wk  = U + 15728640;
  unsigned short* wv  = U + 16777216;
  unsigned short* wp  = U + 17825792;
  unsigned short* wo  = U + 18874368;
  unsigned short* qb  = U + 19922944;        // Q proj
  unsigned short* kb  = U + 24117248;        // K proj
  unsigned short* pb  = U + 28311552;        // P proj
  unsigned short* vpo = U + 30408704;        // V proj
  unsigned short* vTb = pe;                  // aliases pe+wq+wk (dead after projections)
  unsigned short* xb  = qin;                 // attn out (qin dead after projections)
  float* fbase = (float*)(U + 34603008);
  float* uk = fbase;                         // 65536 floats
  float* vp = fbase + 65536;                 // 32768 floats

  const dim3 blk(256);
  const dim3 blk512(512);

  // 1. convert everything to bf16 (one HBM-bound pass)
  convert_kernel<<<dim3(9728), blk, 0, stream>>>(
      query, key_, value, pos_emb, Wq, Wk, Wv, Wp, Wo,
      qin, kin, vin, pe, wq, wk, wv, wp, wo);

  // 2. fused Q,K,V,P projections, depth-2 pipelined, 3-buffer (3 blocks/CU)
  GemmJobs jobs;
  jobs.j[0] = GemmJob{qin, wq, bq, qb, 32};
  jobs.j[1] = GemmJob{kin, wk, bk, kb, 32};
  jobs.j[2] = GemmJob{vin, wv, bv, vpo, 32};
  jobs.j[3] = GemmJob{pe,  wp, nullptr, pb, 16};
  gemm_qkvp<<<dim3(8, 32, 4), blk512, 0, stream>>>(jobs);

  // 3. fused transpose V + rank-1 bias dots (one launch)
  transpose_precompute<<<dim3(896), blk, 0, stream>>>(
      vpo, vTb, kb, pb, pbu, pbv, uk, vp);

  // 4. fused attention (writes into dead qin buffer)
  attn_kernel<<<dim3(16, 16, 4), blk, 0, stream>>>(qb, kb, pb, vTb, uk, vp, xb);

  // 5. output projection -> fp32 d_out, 8-wave depth-2 pipelined
  gemm_one<0><<<dim3(8, 32), blk512, 0, stream>>>(xb, wo, bo, out);
}